// Round 12
// baseline (353.803 us; speedup 1.0000x reference)
//
#include <hip/hip_runtime.h>
#include <hip/hip_bf16.h>
#include <math.h>

// ---------------------------------------------------------------------------
// RankGNN R26: revert R25's agg+GEMM fusion (k_aggg 82us: barrier-coupling
// 16 Poisson(16) nodes per block makes every block run at E[max deg]~27 vs
// mean 16 => 1.7x agg inflation, exactly offsetting the deleted GEMMs).
// Instead fix the GEMMs' real problem -- launch-width starvation (391
// blocks, 1.5/CU, 14.5% occupancy) -- by moving k_gemm1/k_gemm2 to 64
// nodes/block (grid 1563, single 16-row tile per wave, weights register-
// resident, L2-hot). Agg kernels stay barrier-free (R24 shape).
// ---------------------------------------------------------------------------

#define U 128
#define LDA 136    // LDS row stride in bf16 elems (128 + 8 pad)
#define WB 9       // log2(window) = 512 nodes per level-2 window
#define WSZ 512
#define NJ1 512    // level-1 blocks (edge chunks)

typedef __attribute__((ext_vector_type(8))) short bf16x8;
typedef __attribute__((ext_vector_type(4))) float f32x4;
typedef __attribute__((ext_vector_type(2))) float f32x2;

__device__ __forceinline__ unsigned short f2bf(float f) {
    unsigned u = __float_as_uint(f);
    unsigned r = (u + 0x7fffu + ((u >> 16) & 1u)) >> 16;  // RNE
    return (unsigned short)r;
}
__device__ __forceinline__ float bf2f(unsigned short u) {
    return __uint_as_float((unsigned)u << 16);
}
__device__ __forceinline__ unsigned char f2fp8(float v) {
    return (unsigned char)(__builtin_amdgcn_cvt_pk_fp8_f32(v, v, 0, false) & 0xff);
}
__device__ __forceinline__ float ftanh(float x) {
    float cx = fminf(fmaxf(x, -9.0f), 9.0f);
    float t = __expf(2.0f * cx);
    return (t - 1.0f) / (t + 1.0f);
}
// unpack uint4 = 16 fp8 feats into 8 f32x2 accumulators (v_pk_add_f32)
__device__ __forceinline__ void acc16(f32x2* a, uint4 u) {
    a[0] += __builtin_amdgcn_cvt_pk_f32_fp8(u.x, false);
    a[1] += __builtin_amdgcn_cvt_pk_f32_fp8(u.x, true);
    a[2] += __builtin_amdgcn_cvt_pk_f32_fp8(u.y, false);
    a[3] += __builtin_amdgcn_cvt_pk_f32_fp8(u.y, true);
    a[4] += __builtin_amdgcn_cvt_pk_f32_fp8(u.z, false);
    a[5] += __builtin_amdgcn_cvt_pk_f32_fp8(u.z, true);
    a[6] += __builtin_amdgcn_cvt_pk_f32_fp8(u.w, false);
    a[7] += __builtin_amdgcn_cvt_pk_f32_fp8(u.w, true);
}
__device__ __forceinline__ void acc16m(f32x2* a, uint4 u, float m) {
    f32x2 mm = (f32x2){m, m};
    a[0] += mm * __builtin_amdgcn_cvt_pk_f32_fp8(u.x, false);
    a[1] += mm * __builtin_amdgcn_cvt_pk_f32_fp8(u.x, true);
    a[2] += mm * __builtin_amdgcn_cvt_pk_f32_fp8(u.y, false);
    a[3] += mm * __builtin_amdgcn_cvt_pk_f32_fp8(u.y, true);
    a[4] += mm * __builtin_amdgcn_cvt_pk_f32_fp8(u.z, false);
    a[5] += mm * __builtin_amdgcn_cvt_pk_f32_fp8(u.z, true);
    a[6] += mm * __builtin_amdgcn_cvt_pk_f32_fp8(u.w, false);
    a[7] += mm * __builtin_amdgcn_cvt_pk_f32_fp8(u.w, true);
}
// unpack uint2 = 4 bf16 feats, accumulate (shift/mask only)
__device__ __forceinline__ void addbf4(float* a, uint2 u) {
    a[0] += __uint_as_float(u.x << 16);
    a[1] += __uint_as_float(u.x & 0xffff0000u);
    a[2] += __uint_as_float(u.y << 16);
    a[3] += __uint_as_float(u.y & 0xffff0000u);
}
__device__ __forceinline__ void addbf8(float* a, uint4 u) {
    addbf4(a, make_uint2(u.x, u.y));
    addbf4(a + 4, make_uint2(u.z, u.w));
}
__device__ __forceinline__ void addbf8m(float* a, uint4 u, float w) {
    a[0] += w * __uint_as_float(u.x << 16);
    a[1] += w * __uint_as_float(u.x & 0xffff0000u);
    a[2] += w * __uint_as_float(u.y << 16);
    a[3] += w * __uint_as_float(u.y & 0xffff0000u);
    a[4] += w * __uint_as_float(u.z << 16);
    a[5] += w * __uint_as_float(u.z & 0xffff0000u);
    a[6] += w * __uint_as_float(u.w << 16);
    a[7] += w * __uint_as_float(u.w & 0xffff0000u);
}

// ---------------- level-1: window histogram + weight transposes -------------
__global__ __launch_bounds__(256) void k_hist1(const int* __restrict__ dst,
                                               int* __restrict__ hist_g,
                                               const float* __restrict__ W_in,
                                               const float* __restrict__ W1,
                                               const float* __restrict__ W2,
                                               const float* __restrict__ Wf1,
                                               const float* __restrict__ Wf2,
                                               unsigned short* __restrict__ Wint,
                                               unsigned short* __restrict__ W1t,
                                               unsigned short* __restrict__ W2t,
                                               unsigned short* __restrict__ Wf1t,
                                               unsigned short* __restrict__ Wf2t,
                                               int E, int nw) {
    __shared__ int h[256];  // nw <= 256
    int b = blockIdx.x;
    // fold former k_prep weight transposes (independent work)
    int gid = b * 256 + threadIdx.x;
    if (gid < 16384) {
        int n = gid >> 7, k = gid & 127;
        W1t[n * 128 + k] = f2bf(W1[k * 128 + n]);
        Wf1t[n * 128 + k] = f2bf(Wf1[k * 128 + n]);
    } else if (gid < 32768) {
        int i = gid - 16384, n = i >> 7, k = i & 127;
        W2t[n * 128 + k] = f2bf(W2[k * 128 + n]);
    } else if (gid < 36864) {
        int i = gid - 32768, n = i >> 7, k = i & 127;
        Wf2t[n * 128 + k] = f2bf(Wf2[k * 32 + n]);
    } else if (gid < 40960) {
        int i = gid - 36864, c = i >> 5, k = i & 31;  // W_int[c][k], K padded
        Wint[c * 32 + k] = (k < 9) ? f2bf(W_in[k * 128 + c]) : (unsigned short)0;
    }
    for (int i = threadIdx.x; i < nw; i += 256) h[i] = 0;
    __syncthreads();
    int ch = (E + NJ1 - 1) / NJ1;
    int e0 = b * ch, e1 = min(e0 + ch, E);
    // 4 consecutive edges per thread per iter (int4 loads)
    for (int i = e0 + threadIdx.x * 4; i < e1; i += 1024) {
        if (i + 3 < e1) {
            int4 d = *(const int4*)(dst + i);
            atomicAdd(&h[d.x >> WB], 1);
            atomicAdd(&h[d.y >> WB], 1);
            atomicAdd(&h[d.z >> WB], 1);
            atomicAdd(&h[d.w >> WB], 1);
        } else {
            for (int j = i; j < e1; ++j) atomicAdd(&h[dst[j] >> WB], 1);
        }
    }
    __syncthreads();
    for (int w = threadIdx.x; w < nw; w += 256) hist_g[w * NJ1 + b] = h[w];
}

// ---------------- local exclusive scan (in place) + block sums --------------
__global__ __launch_bounds__(256) void k_escan1(int* __restrict__ a,
                                                int* __restrict__ bsum, int n) {
    __shared__ int sc[256];
    int t = threadIdx.x, b = blockIdx.x;
    int base = b * 1024 + t * 4;
    int v[4];
    int s = 0;
    #pragma unroll
    for (int j = 0; j < 4; ++j) {
        int idx = base + j;
        int d = (idx < n) ? a[idx] : 0;
        v[j] = s;  // exclusive within thread
        s += d;
    }
    sc[t] = s;
    __syncthreads();
    for (int off = 1; off < 256; off <<= 1) {
        int x = (t >= off) ? sc[t - off] : 0;
        __syncthreads();
        sc[t] += x;
        __syncthreads();
    }
    int excl = sc[t] - s;
    #pragma unroll
    for (int j = 0; j < 4; ++j) {
        int idx = base + j;
        if (idx < n) a[idx] = v[j] + excl;
    }
    if (t == 255) bsum[b] = sc[255];
}

// ---------------- tiny 1-block exclusive scan of block sums -----------------
__global__ __launch_bounds__(256) void k_scanb(int* __restrict__ a, int nb) {
    __shared__ int sc[256];
    int t = threadIdx.x;
    int v = (t < nb) ? a[t] : 0;
    sc[t] = v;
    __syncthreads();
    for (int off = 1; off < 256; off <<= 1) {
        int u = (t >= off) ? sc[t - off] : 0;
        __syncthreads();
        sc[t] += u;
        __syncthreads();
    }
    if (t < nb) a[t] = sc[t] - v;  // exclusive
}

// ---------------- level-1: bucket edges window-major (packed 32-bit) --------
__global__ __launch_bounds__(256) void k_bucket(const int* __restrict__ src,
                                                const int* __restrict__ dst,
                                                const int* __restrict__ hist_g,
                                                const int* __restrict__ bsum2,
                                                unsigned* __restrict__ eb, int E, int nw) {
    __shared__ int lcur[256];
    int b = blockIdx.x;
    for (int w = threadIdx.x; w < nw; w += 256) {
        int idx = w * NJ1 + b;
        lcur[w] = hist_g[idx] + bsum2[idx >> 10];
    }
    __syncthreads();
    int ch = (E + NJ1 - 1) / NJ1;
    int e0 = b * ch, e1 = min(e0 + ch, E);
    // 4 consecutive edges per thread per iter (int4 loads)
    for (int i = e0 + threadIdx.x * 4; i < e1; i += 1024) {
        if (i + 3 < e1) {
            int4 d = *(const int4*)(dst + i);
            int4 s = *(const int4*)(src + i);
            int p0 = atomicAdd(&lcur[d.x >> WB], 1);
            eb[p0] = ((unsigned)s.x << WB) | (unsigned)(d.x & (WSZ - 1));
            int p1 = atomicAdd(&lcur[d.y >> WB], 1);
            eb[p1] = ((unsigned)s.y << WB) | (unsigned)(d.y & (WSZ - 1));
            int p2 = atomicAdd(&lcur[d.z >> WB], 1);
            eb[p2] = ((unsigned)s.z << WB) | (unsigned)(d.z & (WSZ - 1));
            int p3 = atomicAdd(&lcur[d.w >> WB], 1);
            eb[p3] = ((unsigned)s.w << WB) | (unsigned)(d.w & (WSZ - 1));
        } else {
            for (int j = i; j < e1; ++j) {
                int d = dst[j];
                int pos = atomicAdd(&lcur[d >> WB], 1);
                eb[pos] = ((unsigned)src[j] << WB) | (unsigned)(d & (WSZ - 1));
            }
        }
    }
}

// ---------------- fused CSR: hist + scan + scatter + dinv + xs + cnt --------
__global__ __launch_bounds__(256) void k_csr(const unsigned* __restrict__ eb,
                                             const int* __restrict__ hist_g,
                                             const int* __restrict__ bsum2,
                                             const float* __restrict__ x,
                                             const int* __restrict__ batch,
                                             int* __restrict__ rowptr,
                                             int* __restrict__ csr_src,
                                             float* __restrict__ dinv,
                                             unsigned short* __restrict__ xs,
                                             int* __restrict__ cnt,
                                             int E, int nw, int N, int G) {
    __shared__ int h[WSZ];
    __shared__ int cur[WSZ];
    __shared__ int sc[256];
    __shared__ int cbin[32];
    const int w = blockIdx.x;
    const int t = threadIdx.x;
    h[t] = 0;
    h[t + 256] = 0;
    if (t < 32) cbin[t] = 0;
    __syncthreads();
    const int wi0 = w * NJ1;
    const int s0 = hist_g[wi0] + bsum2[wi0 >> 10];
    int s1;
    if (w + 1 < nw) {
        const int wi1 = (w + 1) * NJ1;
        s1 = hist_g[wi1] + bsum2[wi1 >> 10];
    } else {
        s1 = E;
    }
    // histogram pass: 4 consecutive eb entries per thread per iter
    for (int i = s0 + t * 4; i < s1; i += 1024) {
        if (i + 3 < s1) {
            uint4 e4 = *(const uint4*)(eb + i);
            atomicAdd(&h[e4.x & (WSZ - 1)], 1);
            atomicAdd(&h[e4.y & (WSZ - 1)], 1);
            atomicAdd(&h[e4.z & (WSZ - 1)], 1);
            atomicAdd(&h[e4.w & (WSZ - 1)], 1);
        } else {
            for (int j = i; j < s1; ++j) atomicAdd(&h[eb[j] & (WSZ - 1)], 1);
        }
    }
    __syncthreads();
    // pair-scan: thread t owns nodes 2t, 2t+1
    int h0 = h[2 * t], h1 = h[2 * t + 1];
    int ps = h0 + h1;
    sc[t] = ps;
    __syncthreads();
    for (int off = 1; off < 256; off <<= 1) {
        int xv = (t >= off) ? sc[t - off] : 0;
        __syncthreads();
        sc[t] += xv;
        __syncthreads();
    }
    int excl = sc[t] - ps;
    const int base = w << WB;
    int p0 = s0 + excl, p1 = p0 + h0;
    cur[2 * t] = p0;
    cur[2 * t + 1] = p1;
    int n0i = base + 2 * t, n1i = n0i + 1;
    const int g_lo = batch[base];
    float dv0 = 0.f, dv1 = 0.f;
    if (n0i < N) {
        rowptr[n0i] = p0;
        dv0 = rsqrtf((float)h0 + 1.0f);
        dinv[n0i] = dv0;
        int b0 = batch[n0i] - g_lo;
        if ((unsigned)b0 < 32u) atomicAdd(&cbin[b0], 1);
        else atomicAdd(&cnt[batch[n0i]], 1);
    }
    if (n1i < N) {
        rowptr[n1i] = p1;
        dv1 = rsqrtf((float)h1 + 1.0f);
        dinv[n1i] = dv1;
        int b1 = batch[n1i] - g_lo;
        if ((unsigned)b1 < 32u) atomicAdd(&cbin[b1], 1);
        else atomicAdd(&cnt[batch[n1i]], 1);
    }
    if (w == nw - 1 && t == 255) rowptr[N] = E;
    // xs rows (bf16, 32B)
    if (n0i < N) {
        #pragma unroll
        for (int k = 0; k < 9; ++k) xs[n0i * 16 + k] = f2bf(x[(size_t)n0i * 9 + k] * dv0);
        #pragma unroll
        for (int k = 9; k < 16; ++k) xs[n0i * 16 + k] = 0;
    }
    if (n1i < N) {
        #pragma unroll
        for (int k = 0; k < 9; ++k) xs[n1i * 16 + k] = f2bf(x[(size_t)n1i * 9 + k] * dv1);
        #pragma unroll
        for (int k = 9; k < 16; ++k) xs[n1i * 16 + k] = 0;
    }
    __syncthreads();
    if (t < 32 && cbin[t] > 0) {
        int g = g_lo + t;
        if (g < G) atomicAdd(&cnt[g], cbin[t]);
    }
    // scatter pass: 4 consecutive eb entries per thread per iter (L2-hot)
    for (int i = s0 + t * 4; i < s1; i += 1024) {
        if (i + 3 < s1) {
            uint4 e4 = *(const uint4*)(eb + i);
            int q0 = atomicAdd(&cur[e4.x & (WSZ - 1)], 1);
            csr_src[q0] = (int)(e4.x >> WB);
            int q1 = atomicAdd(&cur[e4.y & (WSZ - 1)], 1);
            csr_src[q1] = (int)(e4.y >> WB);
            int q2 = atomicAdd(&cur[e4.z & (WSZ - 1)], 1);
            csr_src[q2] = (int)(e4.z >> WB);
            int q3 = atomicAdd(&cur[e4.w & (WSZ - 1)], 1);
            csr_src[q3] = (int)(e4.w >> WB);
        } else {
            for (int j = i; j < s1; ++j) {
                unsigned ep = eb[j];
                int pos = atomicAdd(&cur[ep & (WSZ - 1)], 1);
                csr_src[pos] = (int)(ep >> WB);
            }
        }
    }
}

// ---------------- layer-1 agg: 2 lanes x uint4 per row, 16 edge slots -------
__global__ __launch_bounds__(256) void k_aggx(const unsigned short* __restrict__ xs,
                                              const int* __restrict__ rowptr,
                                              const int* __restrict__ csr_src,
                                              const float* __restrict__ dinv,
                                              unsigned short* __restrict__ xab, int N) {
    int wv = threadIdx.x >> 6;
    int n0 = blockIdx.x * 8 + wv * 2;
    if (n0 >= N) return;
    int lane = threadIdx.x & 63;
    int h = lane >> 5;
    int es = (lane >> 1) & 15;
    int o = lane & 1;
    int n = n0 + h;
    bool valid = (n < N);
    if (!valid) n = n0;
    const uint4* xs4 = (const uint4*)xs;  // row = 2 x uint4 (32 B)
    float a[8] = {0.f, 0.f, 0.f, 0.f, 0.f, 0.f, 0.f, 0.f};
    int s = rowptr[n], e = rowptr[n + 1];
    int i = s;
    while (i + 32 <= e) {
        int idx0 = csr_src[i + es];
        int idx1 = csr_src[i + 16 + es];
        uint4 u0 = xs4[(unsigned)idx0 * 2 + o];
        uint4 u1 = xs4[(unsigned)idx1 * 2 + o];
        addbf8(a, u0);
        addbf8(a, u1);
        i += 32;
    }
    if (i < e) {
        int k0 = i + es, k1 = i + 16 + es;
        float w0 = (k0 < e) ? 1.0f : 0.0f;
        float w1 = (k1 < e) ? 1.0f : 0.0f;
        int i0 = (k0 < e) ? k0 : (e - 1);
        int i1 = (k1 < e) ? k1 : (e - 1);
        int idx0 = csr_src[i0];
        int idx1 = csr_src[i1];
        uint4 u0 = xs4[(unsigned)idx0 * 2 + o];
        uint4 u1 = xs4[(unsigned)idx1 * 2 + o];
        addbf8m(a, u0, w0);
        addbf8m(a, u1, w1);
    }
    #pragma unroll
    for (int j = 0; j < 8; ++j) {
        a[j] += __shfl_xor(a[j], 2);
        a[j] += __shfl_xor(a[j], 4);
        a[j] += __shfl_xor(a[j], 8);
        a[j] += __shfl_xor(a[j], 16);
    }
    if (valid && es == 0) {
        uint4 u = xs4[(unsigned)n * 2 + o];  // self
        addbf8(a, u);
        float dv = dinv[n];
        uint4 st;
        st.x = (unsigned)f2bf(dv * a[0]) | ((unsigned)f2bf(dv * a[1]) << 16);
        st.y = (unsigned)f2bf(dv * a[2]) | ((unsigned)f2bf(dv * a[3]) << 16);
        st.z = (unsigned)f2bf(dv * a[4]) | ((unsigned)f2bf(dv * a[5]) << 16);
        st.w = (unsigned)f2bf(dv * a[6]) | ((unsigned)f2bf(dv * a[7]) << 16);
        *(uint4*)(xab + (size_t)n * 16 + 8 * o) = st;
    }
}

// ---------------- fused layer-1 GEMM + layer-2 MFMA -> fp8 (64 nodes/blk) ---
__global__ __launch_bounds__(256, 2) void k_gemm1(const unsigned short* __restrict__ xab,
                                                  const unsigned short* __restrict__ Wint,
                                                  const float* __restrict__ bin,
                                                  const unsigned short* __restrict__ Wt,
                                                  const float* __restrict__ dinv,
                                                  unsigned char* __restrict__ Out, int N) {
    __shared__ unsigned short H2[4][16 * LDA];
    const int tid = threadIdx.x;
    const int wave = tid >> 6, lane = tid & 63;
    const int m16 = lane & 15, q = lane >> 4;
    // preload weights once per wave (L2-hot across 1563 blocks)
    bf16x8 w2r[4][8], w1r[8];
    #pragma unroll
    for (int kc = 0; kc < 4; ++kc)
        #pragma unroll
        for (int t = 0; t < 8; ++t)
            w2r[kc][t] = *(const bf16x8*)(Wt + ((t * 16 + m16) * 128 + kc * 32 + q * 8));
    #pragma unroll
    for (int t = 0; t < 8; ++t)
        w1r[t] = *(const bf16x8*)(Wint + ((t * 16 + m16) * 32 + q * 8));
    float b1v[8];
    #pragma unroll
    for (int t = 0; t < 8; ++t) b1v[t] = bin[t * 16 + m16];
    unsigned short* h2s = H2[wave];
    const int row0 = blockIdx.x * 64 + wave * 16;
    int arow = row0 + m16;
    if (arow >= N) arow = N - 1;
    bf16x8 a1;
    if (q < 2) a1 = *(const bf16x8*)(xab + (size_t)arow * 16 + q * 8);
    else a1 = (bf16x8){0, 0, 0, 0, 0, 0, 0, 0};
    f32x4 acc1[8];
    #pragma unroll
    for (int t = 0; t < 8; ++t) acc1[t] = (f32x4){0.f, 0.f, 0.f, 0.f};
    #pragma unroll
    for (int t = 0; t < 8; ++t)
        acc1[t] = __builtin_amdgcn_mfma_f32_16x16x32_bf16(a1, w1r[t], acc1[t], 0, 0, 0);
    #pragma unroll
    for (int t = 0; t < 8; ++t) {
        #pragma unroll
        for (int r = 0; r < 4; ++r)
            h2s[(q * 4 + r) * LDA + t * 16 + m16] = f2bf(ftanh(acc1[t][r] + b1v[t]));
    }
    const unsigned short* h2row = h2s + m16 * LDA + q * 8;
    f32x4 acc[8];
    #pragma unroll
    for (int t = 0; t < 8; ++t) acc[t] = (f32x4){0.f, 0.f, 0.f, 0.f};
    #pragma unroll
    for (int kc = 0; kc < 4; ++kc) {
        bf16x8 af = *(const bf16x8*)(h2row + kc * 32);
        #pragma unroll
        for (int t = 0; t < 8; ++t)
            acc[t] = __builtin_amdgcn_mfma_f32_16x16x32_bf16(af, w2r[kc][t], acc[t], 0, 0, 0);
    }
    float dv[4];
    #pragma unroll
    for (int r = 0; r < 4; ++r) {
        int gr = row0 + q * 4 + r;
        dv[r] = (gr < N) ? dinv[gr] : 0.0f;
    }
    #pragma unroll
    for (int t = 0; t < 8; ++t) {
        #pragma unroll
        for (int r = 0; r < 4; ++r) {
            int gr = row0 + q * 4 + r;
            if (gr < N) Out[(size_t)gr * U + t * 16 + m16] = f2fp8(acc[t][r] * dv[r]);
        }
    }
}

// ---------------- layer-3 GEMM (64 nodes/blk): fp8(dinv * (A @ Wt^T)) -------
__global__ __launch_bounds__(256, 2) void k_gemm2(const unsigned short* __restrict__ A,
                                                  const unsigned short* __restrict__ Wt,
                                                  const float* __restrict__ dinv,
                                                  unsigned char* __restrict__ Out, int N) {
    const int tid = threadIdx.x;
    const int wave = tid >> 6, lane = tid & 63;
    const int m16 = lane & 15, q = lane >> 4;
    const int row0 = blockIdx.x * 64 + wave * 16;
    int ar = row0 + m16;
    if (ar >= N) ar = N - 1;
    const bf16x8* arow = (const bf16x8*)(A + (size_t)ar * U + q * 8);
    bf16x8 a[4];
    #pragma unroll
    for (int kc = 0; kc < 4; ++kc) a[kc] = arow[kc * 4];
    bf16x8 wr[4][8];
    #pragma unroll
    for (int kc = 0; kc < 4; ++kc)
        #pragma unroll
        for (int t = 0; t < 8; ++t)
            wr[kc][t] = *(const bf16x8*)(Wt + ((t * 16 + m16) * 128 + kc * 32 + q * 8));
    f32x4 acc[8];
    #pragma unroll
    for (int t = 0; t < 8; ++t) acc[t] = (f32x4){0.f, 0.f, 0.f, 0.f};
    #pragma unroll
    for (int kc = 0; kc < 4; ++kc) {
        #pragma unroll
        for (int t = 0; t < 8; ++t)
            acc[t] = __builtin_amdgcn_mfma_f32_16x16x32_bf16(a[kc], wr[kc][t], acc[t], 0, 0, 0);
    }
    float dv[4];
    #pragma unroll
    for (int r = 0; r < 4; ++r) {
        int gr = row0 + q * 4 + r;
        dv[r] = (gr < N) ? dinv[gr] : 0.0f;
    }
    #pragma unroll
    for (int t = 0; t < 8; ++t) {
        #pragma unroll
        for (int r = 0; r < 4; ++r) {
            int gr = row0 + q * 4 + r;
            if (gr < N) Out[(size_t)gr * U + t * 16 + m16] = f2fp8(acc[t][r] * dv[r]);
        }
    }
}

// ---------------- aggregation (fp8 table): uint4 rows, half-wave per node ---
__global__ __launch_bounds__(256) void k_aggb(const unsigned char* __restrict__ Tb,
                                              const int* __restrict__ rowptr,
                                              const int* __restrict__ csr_src,
                                              const float* __restrict__ dinv,
                                              const float* __restrict__ bias,
                                              unsigned short* __restrict__ Out, int N) {
    int wv = threadIdx.x >> 6;
    int n0 = blockIdx.x * 8 + wv * 2;
    if (n0 >= N) return;
    int lane = threadIdx.x & 63;
    int h = lane >> 5;
    int q = (lane >> 3) & 3;
    int o = lane & 7;
    int n = n0 + h;
    bool valid = (n < N);
    if (!valid) n = n0;
    const char* Tc = (const char*)Tb;
    const unsigned loff = (unsigned)o << 4;  // byte offset of my uint4 in row
    f32x2 acc[8];
    #pragma unroll
    for (int j = 0; j < 8; ++j) acc[j] = (f32x2){0.f, 0.f};
    int s = rowptr[n], e = rowptr[n + 1];
    int i = s;
    while (i + 16 <= e) {
        int idx[4];
        #pragma unroll
        for (int g2 = 0; g2 < 4; ++g2) idx[g2] = csr_src[i + g2 * 4 + q];
        uint4 u[4];
        #pragma unroll
        for (int g2 = 0; g2 < 4; ++g2)
            u[g2] = *(const uint4*)(Tc + (((unsigned)idx[g2] << 7) + loff));
        #pragma unroll
        for (int g2 = 0; g2 < 4; ++g2) acc16(acc, u[g2]);
        i += 16;
    }
    if (i < e) {
        int ii[4];
        float w[4];
        #pragma unroll
        for (int g2 = 0; g2 < 4; ++g2) {
            int k = i + g2 * 4 + q;
            w[g2] = (k < e) ? 1.0f : 0.0f;
            ii[g2] = (k < e) ? k : (e - 1);
        }
        int idx[4];
        #pragma unroll
        for (int g2 = 0; g2 < 4; ++g2) idx[g2] = csr_src[ii[g2]];
        uint4 u[4];
        #pragma unroll
        for (int g2 = 0; g2 < 4; ++g2)
            u[g2] = *(const uint4*)(Tc + (((unsigned)idx[g2] << 7) + loff));
        #pragma unroll
        for (int g2 = 0; g2 < 4; ++g2) acc16m(acc, u[g2], w[g2]);
    }
    float* af = (float*)acc;
    #pragma unroll
    for (int j = 0; j < 16; ++j) {
        af[j] += __shfl_xor(af[j], 8);
        af[j] += __shfl_xor(af[j], 16);
    }
    f32x2 vA = (q < 2) ? ((q == 0) ? acc[0] : acc[2]) : ((q == 2) ? acc[4] : acc[6]);
    f32x2 vB = (q < 2) ? ((q == 0) ? acc[1] : acc[3]) : ((q == 2) ? acc[5] : acc[7]);
    int f = 16 * o + 4 * q;
    float4 bb = *(const float4*)&bias[f];
    float dv = dinv[n];
    unsigned selfu = *(const unsigned*)(Tc + ((unsigned)n << 7) + f);
    f32x2 s01 = __builtin_amdgcn_cvt_pk_f32_fp8(selfu, false);
    f32x2 s23 = __builtin_amdgcn_cvt_pk_f32_fp8(selfu, true);
    float o0 = ftanh(dv * (vA[0] + s01[0]) + bb.x);
    float o1 = ftanh(dv * (vA[1] + s01[1]) + bb.y);
    float o2 = ftanh(dv * (vB[0] + s23[0]) + bb.z);
    float o3 = ftanh(dv * (vB[1] + s23[1]) + bb.w);
    if (valid) {
        uint2 st;
        st.x = (unsigned)f2bf(o0) | ((unsigned)f2bf(o1) << 16);
        st.y = (unsigned)f2bf(o2) | ((unsigned)f2bf(o3) << 16);
        *(uint2*)((char*)Out + ((size_t)n << 8) + ((unsigned)f << 1)) = st;
    }
}

// ---------------- fused MFMA MLP head v2 (as R9) ----------------
__global__ __launch_bounds__(256, 2) void k_mlp(const unsigned short* __restrict__ H,
                                                const unsigned short* __restrict__ Wf1t,
                                                const float* __restrict__ bf1,
                                                const unsigned short* __restrict__ Wf2t,
                                                const float* __restrict__ bf2,
                                                const float* __restrict__ Wf3,
                                                const float* __restrict__ bf3,
                                                const int* __restrict__ batch,
                                                float* __restrict__ util_sum,
                                                int N, int G) {
    __shared__ unsigned short H2[4][16 * LDA];  // per-wave transpose slice
    __shared__ float gsum[8];
    const int tid = threadIdx.x;
    if (tid < 8) gsum[tid] = 0.0f;
    const int wave = tid >> 6, lane = tid & 63;
    const int m16 = lane & 15, q = lane >> 4;
    const int blk0 = blockIdx.x * 256;
    const int g0 = batch[min(blk0, N - 1)];
    bf16x8 w1[4][8], w2[4][2];
    #pragma unroll
    for (int kc = 0; kc < 4; ++kc) {
        #pragma unroll
        for (int t = 0; t < 8; ++t)
            w1[kc][t] = *(const bf16x8*)(Wf1t + ((t * 16 + m16) * 128 + kc * 32 + q * 8));
        #pragma unroll
        for (int t = 0; t < 2; ++t)
            w2[kc][t] = *(const bf16x8*)(Wf2t + ((t * 16 + m16) * 128 + kc * 32 + q * 8));
    }
    float b1v[8];
    #pragma unroll
    for (int t = 0; t < 8; ++t) b1v[t] = bf1[t * 16 + m16];
    const float b2lo = bf2[m16], b2hi = bf2[m16 + 16];
    const float w3lo = Wf3[m16], w3hi = Wf3[m16 + 16];
    const float bf3v = bf3[0];
    __syncthreads();  // gsum init visible before tile atomics
    unsigned short* h2s = H2[wave];
    const int wbase = blk0 + wave * 64;
    bf16x8 a[4];
    {
        int ar = wbase + m16;
        if (ar >= N) ar = N - 1;
        const bf16x8* arow = (const bf16x8*)(H + (size_t)ar * U + q * 8);
        #pragma unroll
        for (int kc = 0; kc < 4; ++kc) a[kc] = arow[kc * 4];
    }
    for (int tile = 0; tile < 4; ++tile) {
        const int row0 = wbase + tile * 16;
        bf16x8 an[4];
        if (tile < 3) {
            int ar = row0 + 16 + m16;
            if (ar >= N) ar = N - 1;
            const bf16x8* arow = (const bf16x8*)(H + (size_t)ar * U + q * 8);
            #pragma unroll
            for (int kc = 0; kc < 4; ++kc) an[kc] = arow[kc * 4];
        }
        f32x4 acc[8];
        #pragma unroll
        for (int t = 0; t < 8; ++t) acc[t] = (f32x4){0.f, 0.f, 0.f, 0.f};
        #pragma unroll
        for (int kc = 0; kc < 4; ++kc) {
            #pragma unroll
            for (int t = 0; t < 8; ++t)
                acc[t] = __builtin_amdgcn_mfma_f32_16x16x32_bf16(a[kc], w1[kc][t], acc[t], 0, 0, 0);
        }
        #pragma unroll
        for (int t = 0; t < 8; ++t) {
            #pragma unroll
            for (int r = 0; r < 4; ++r) {
                int lr = q * 4 + r;
                h2s[lr * LDA + t * 16 + m16] = f2bf(ftanh(acc[t][r] + b1v[t]));
            }
        }
        f32x4 acc2[2];
        acc2[0] = (f32x4){0.f, 0.f, 0.f, 0.f};
        acc2[1] = (f32x4){0.f, 0.f, 0.f, 0.f};
        const unsigned short* h2row = h2s + m16 * LDA + q * 8;
        #pragma unroll
        for (int kc = 0; kc < 4; ++kc) {
            bf16x8 af = *(const bf16x8*)(h2row + kc * 32);
            #pragma unroll
            for (int t = 0; t < 2; ++t)
                acc2[t] = __builtin_amdgcn_mfma_f32_16x16x32_bf16(af, w2[kc][t], acc2[t], 0, 0, 0);
        }
        #pragma unroll
        for (int r = 0; r < 4; ++r) {
            float t0 = ftanh(acc2[0][r] + b2lo);
            float t1 = ftanh(acc2[1][r] + b2hi);
            float v = t0 * w3lo + t1 * w3hi;
            v += __shfl_xor(v, 1);
            v += __shfl_xor(v, 2);
            v += __shfl_xor(v, 4);
            v += __shfl_xor(v, 8);
            if (m16 == 0) {
                int n = row0 + q * 4 + r;
                if (n < N) atomicAdd(&gsum[batch[n] - g0], v + bf3v);
            }
        }
        #pragma unroll
        for (int kc = 0; kc < 4; ++kc) a[kc] = an[kc];
    }
    __syncthreads();
    if (tid < 8) {
        int g = g0 + tid;
        if (g < G) {
            float s = gsum[tid];
            if (s != 0.0f) atomicAdd(&util_sum[g], s);
        }
    }
}

// ---------------- fused output: util + pair sigmoid ----------------
__global__ void k_out(const float* __restrict__ us, const int* __restrict__ cnt,
                      const int* __restrict__ ia, const int* __restrict__ ib,
                      float* __restrict__ out, int P, int G) {
    int t = blockIdx.x * 256 + threadIdx.x;
    if (t < G) out[P + t] = us[t] / fmaxf((float)cnt[t], 1.0f);
    if (t < P) {
        int a = ia[t], b = ib[t];
        float ua = us[a] / fmaxf((float)cnt[a], 1.0f);
        float ub = us[b] / fmaxf((float)cnt[b], 1.0f);
        out[t] = 1.0f / (1.0f + expf(-(ub - ua)));
    }
}

extern "C" void kernel_launch(void* const* d_in, const int* in_sizes, int n_in,
                              void* d_out, int out_size, void* d_ws, size_t ws_size,
                              hipStream_t stream) {
    const float* x     = (const float*)d_in[0];
    const int*   eidx  = (const int*)d_in[1];
    const int*   batch = (const int*)d_in[2];
    const int*   idx_a = (const int*)d_in[3];
    const int*   idx_b = (const int*)d_in[4];
    const float* W_in  = (const float*)d_in[5];
    const float* b_in  = (const float*)d_in[6];
    const float* W1    = (const float*)d_in[7];
    const float* b1    = (const float*)d_in[8];
    const float* W2    = (const float*)d_in[9];
    const float* b2    = (const float*)d_in[10];
    const float* Wf1   = (const float*)d_in[11];
    const float* bf1   = (const float*)d_in[12];
    const float* Wf2   = (const float*)d_in[13];
    const float* bf2   = (const float*)d_in[14];
    const float* Wf3   = (const float*)d_in[15];
    const float* bf3   = (const float*)d_in[16];
    float* out = (float*)d_out;

    const int N = in_sizes[0] / 9;
    const int E = in_sizes[1] / 2;
    const int P = in_sizes[3];
    const int G = out_size - P;

    const int* src = eidx;
    const int* dst = eidx + E;

    const int nw = (N + WSZ - 1) >> WB;  // level-2 windows (196 for N=100k)
    const int nh = nw * NJ1;             // hist_g size
    const int nbh = (nh + 1023) / 1024;  // scan blocks for hist_g

    // ---- workspace carve-out ----
    char* ws = (char*)d_ws;
    size_t off = 0;
    auto take = [&](size_t bytes) -> void* {
        void* p = ws + off;
        off = (off + bytes + 255) & ~(size_t)255;
        return p;
    };
    float* dinv     = (float*)take((size_t)N * 4);
    int*   rowptr   = (int*)  take((size_t)(N + 1) * 4);
    int*   bsum2    = (int*)  take(256 * 4);
    int*   hist_g   = (int*)  take((size_t)nh * 4);
    unsigned* eb    = (unsigned*)take((size_t)E * 4);   // packed (src<<9)|dloc
    int*   csr_src  = (int*)  take((size_t)E * 4);
    unsigned short* xs  = (unsigned short*)take((size_t)N * 16 * 2);  // bf16 32B rows
    unsigned short* xab = (unsigned short*)take((size_t)N * 16 * 2);  // bf16 A-frag rows
    unsigned short* bufA = (unsigned short*)take((size_t)N * U * 2);  // bf16 acts
    unsigned char*  Tb   = (unsigned char*) take((size_t)N * U);      // fp8 table
    unsigned short* Wint = (unsigned short*)take(128 * 32 * 2);       // W_in^T pad K=32
    unsigned short* W1t  = (unsigned short*)take(128 * 128 * 2);
    unsigned short* W2t  = (unsigned short*)take(128 * 128 * 2);
    unsigned short* Wf1t = (unsigned short*)take(128 * 128 * 2);
    unsigned short* Wf2t = (unsigned short*)take(32 * 128 * 2);
    // zero-region: util_sum + cnt contiguous, single memset
    float* util_sum = (float*)take((size_t)G * 8);
    int*   cnt      = (int*)(util_sum + G);
    (void)ws_size;

    hipMemsetAsync(util_sum, 0, (size_t)G * 8, stream);

    // ---- CSR build: two-level counting sort, fused window CSR ----
    k_hist1<<<NJ1, 256, 0, stream>>>(dst, hist_g, W_in, W1, W2, Wf1, Wf2,
                                     Wint, W1t, W2t, Wf1t, Wf2t, E, nw);
    k_escan1<<<nbh, 256, 0, stream>>>(hist_g, bsum2, nh);
    k_scanb<<<1, 256, 0, stream>>>(bsum2, nbh);
    k_bucket<<<NJ1, 256, 0, stream>>>(src, dst, hist_g, bsum2, eb, E, nw);
    k_csr<<<nw, 256, 0, stream>>>(eb, hist_g, bsum2, x, batch, rowptr, csr_src,
                                  dinv, xs, cnt, E, nw, N, G);

    const int gemmGrid = (N + 63) / 64;  // 64 nodes/block (grid 1563)
    const int aggGrid = (N + 7) / 8;     // 2 nodes/wave, 8 nodes/block

    // ---- GCN layer 1 agg + fused layer-1/layer-2 GEMM -> fp8 ----
    k_aggx<<<aggGrid, 256, 0, stream>>>(xs, rowptr, csr_src, dinv, xab, N);
    k_gemm1<<<gemmGrid, 256, 0, stream>>>(xab, Wint, b_in, W1t, dinv, Tb, N);
    k_aggb<<<aggGrid, 256, 0, stream>>>(Tb, rowptr, csr_src, dinv, b1, bufA, N);
    // ---- GCN layer 3 ----
    k_gemm2<<<gemmGrid, 256, 0, stream>>>(bufA, W2t, dinv, Tb, N);
    k_aggb<<<aggGrid, 256, 0, stream>>>(Tb, rowptr, csr_src, dinv, b2, bufA, N);

    // ---- MLP head + pooled sums (256 nodes/block) ----
    k_mlp<<<(N + 255) / 256, 256, 0, stream>>>(bufA, Wf1t, bf1, Wf2t, bf2, Wf3, bf3,
                                               batch, util_sum, N, G);

    // ---- fused util + pairs ----
    int mx = (P > G ? P : G);
    k_out<<<(mx + 255) / 256, 256, 0, stream>>>(util_sum, cnt, idx_a, idx_b, out, P, G);
}

// Round 13
// 311.235 us; speedup vs baseline: 1.1368x; 1.1368x over previous
//
#include <hip/hip_runtime.h>
#include <hip/hip_bf16.h>
#include <math.h>

// ---------------------------------------------------------------------------
// RankGNN R27: gemm kernels rebuilt with LDS-resident weights. R26's VGPR=96
// proved the compiler sinks the 160-VGPR weight preload back into the MFMA
// loop (no scratch, loads rematerialized from L2) -> every variant was
// latency-bound on ~40 L2 loads/tile with ~1-2 blocks/CU. Now: W1t/W2t
// staged to LDS once per block (32KB cooperative copy, XOR row swizzle ->
// ~2-way conflicts), Wint+bias in regs, 128 nodes/block (grid 782, 2 tiles/
// wave). Rest identical to R24 (best: 329us).
// ---------------------------------------------------------------------------

#define U 128
#define LDA 136    // LDS row stride in bf16 elems (128 + 8 pad)
#define WB 9       // log2(window) = 512 nodes per level-2 window
#define WSZ 512
#define NJ1 512    // level-1 blocks (edge chunks)

typedef __attribute__((ext_vector_type(8))) short bf16x8;
typedef __attribute__((ext_vector_type(4))) float f32x4;
typedef __attribute__((ext_vector_type(2))) float f32x2;

__device__ __forceinline__ unsigned short f2bf(float f) {
    unsigned u = __float_as_uint(f);
    unsigned r = (u + 0x7fffu + ((u >> 16) & 1u)) >> 16;  // RNE
    return (unsigned short)r;
}
__device__ __forceinline__ float bf2f(unsigned short u) {
    return __uint_as_float((unsigned)u << 16);
}
__device__ __forceinline__ unsigned char f2fp8(float v) {
    return (unsigned char)(__builtin_amdgcn_cvt_pk_fp8_f32(v, v, 0, false) & 0xff);
}
__device__ __forceinline__ float ftanh(float x) {
    float cx = fminf(fmaxf(x, -9.0f), 9.0f);
    float t = __expf(2.0f * cx);
    return (t - 1.0f) / (t + 1.0f);
}
// unpack uint4 = 16 fp8 feats into 8 f32x2 accumulators (v_pk_add_f32)
__device__ __forceinline__ void acc16(f32x2* a, uint4 u) {
    a[0] += __builtin_amdgcn_cvt_pk_f32_fp8(u.x, false);
    a[1] += __builtin_amdgcn_cvt_pk_f32_fp8(u.x, true);
    a[2] += __builtin_amdgcn_cvt_pk_f32_fp8(u.y, false);
    a[3] += __builtin_amdgcn_cvt_pk_f32_fp8(u.y, true);
    a[4] += __builtin_amdgcn_cvt_pk_f32_fp8(u.z, false);
    a[5] += __builtin_amdgcn_cvt_pk_f32_fp8(u.z, true);
    a[6] += __builtin_amdgcn_cvt_pk_f32_fp8(u.w, false);
    a[7] += __builtin_amdgcn_cvt_pk_f32_fp8(u.w, true);
}
__device__ __forceinline__ void acc16m(f32x2* a, uint4 u, float m) {
    f32x2 mm = (f32x2){m, m};
    a[0] += mm * __builtin_amdgcn_cvt_pk_f32_fp8(u.x, false);
    a[1] += mm * __builtin_amdgcn_cvt_pk_f32_fp8(u.x, true);
    a[2] += mm * __builtin_amdgcn_cvt_pk_f32_fp8(u.y, false);
    a[3] += mm * __builtin_amdgcn_cvt_pk_f32_fp8(u.y, true);
    a[4] += mm * __builtin_amdgcn_cvt_pk_f32_fp8(u.z, false);
    a[5] += mm * __builtin_amdgcn_cvt_pk_f32_fp8(u.z, true);
    a[6] += mm * __builtin_amdgcn_cvt_pk_f32_fp8(u.w, false);
    a[7] += mm * __builtin_amdgcn_cvt_pk_f32_fp8(u.w, true);
}
// unpack uint2 = 4 bf16 feats, accumulate (shift/mask only)
__device__ __forceinline__ void addbf4(float* a, uint2 u) {
    a[0] += __uint_as_float(u.x << 16);
    a[1] += __uint_as_float(u.x & 0xffff0000u);
    a[2] += __uint_as_float(u.y << 16);
    a[3] += __uint_as_float(u.y & 0xffff0000u);
}
__device__ __forceinline__ void addbf8(float* a, uint4 u) {
    addbf4(a, make_uint2(u.x, u.y));
    addbf4(a + 4, make_uint2(u.z, u.w));
}
__device__ __forceinline__ void addbf8m(float* a, uint4 u, float w) {
    a[0] += w * __uint_as_float(u.x << 16);
    a[1] += w * __uint_as_float(u.x & 0xffff0000u);
    a[2] += w * __uint_as_float(u.y << 16);
    a[3] += w * __uint_as_float(u.y & 0xffff0000u);
    a[4] += w * __uint_as_float(u.z << 16);
    a[5] += w * __uint_as_float(u.z & 0xffff0000u);
    a[6] += w * __uint_as_float(u.w << 16);
    a[7] += w * __uint_as_float(u.w & 0xffff0000u);
}

// ---------------- level-1: window histogram + weight transposes -------------
__global__ __launch_bounds__(256) void k_hist1(const int* __restrict__ dst,
                                               int* __restrict__ hist_g,
                                               const float* __restrict__ W_in,
                                               const float* __restrict__ W1,
                                               const float* __restrict__ W2,
                                               const float* __restrict__ Wf1,
                                               const float* __restrict__ Wf2,
                                               unsigned short* __restrict__ Wint,
                                               unsigned short* __restrict__ W1t,
                                               unsigned short* __restrict__ W2t,
                                               unsigned short* __restrict__ Wf1t,
                                               unsigned short* __restrict__ Wf2t,
                                               int E, int nw) {
    __shared__ int h[256];  // nw <= 256
    int b = blockIdx.x;
    // fold former k_prep weight transposes (independent work)
    int gid = b * 256 + threadIdx.x;
    if (gid < 16384) {
        int n = gid >> 7, k = gid & 127;
        W1t[n * 128 + k] = f2bf(W1[k * 128 + n]);
        Wf1t[n * 128 + k] = f2bf(Wf1[k * 128 + n]);
    } else if (gid < 32768) {
        int i = gid - 16384, n = i >> 7, k = i & 127;
        W2t[n * 128 + k] = f2bf(W2[k * 128 + n]);
    } else if (gid < 36864) {
        int i = gid - 32768, n = i >> 7, k = i & 127;
        Wf2t[n * 128 + k] = f2bf(Wf2[k * 32 + n]);
    } else if (gid < 40960) {
        int i = gid - 36864, c = i >> 5, k = i & 31;  // W_int[c][k], K padded
        Wint[c * 32 + k] = (k < 9) ? f2bf(W_in[k * 128 + c]) : (unsigned short)0;
    }
    for (int i = threadIdx.x; i < nw; i += 256) h[i] = 0;
    __syncthreads();
    int ch = (E + NJ1 - 1) / NJ1;
    int e0 = b * ch, e1 = min(e0 + ch, E);
    // 4 consecutive edges per thread per iter (int4 loads)
    for (int i = e0 + threadIdx.x * 4; i < e1; i += 1024) {
        if (i + 3 < e1) {
            int4 d = *(const int4*)(dst + i);
            atomicAdd(&h[d.x >> WB], 1);
            atomicAdd(&h[d.y >> WB], 1);
            atomicAdd(&h[d.z >> WB], 1);
            atomicAdd(&h[d.w >> WB], 1);
        } else {
            for (int j = i; j < e1; ++j) atomicAdd(&h[dst[j] >> WB], 1);
        }
    }
    __syncthreads();
    for (int w = threadIdx.x; w < nw; w += 256) hist_g[w * NJ1 + b] = h[w];
}

// ---------------- local exclusive scan (in place) + block sums --------------
__global__ __launch_bounds__(256) void k_escan1(int* __restrict__ a,
                                                int* __restrict__ bsum, int n) {
    __shared__ int sc[256];
    int t = threadIdx.x, b = blockIdx.x;
    int base = b * 1024 + t * 4;
    int v[4];
    int s = 0;
    #pragma unroll
    for (int j = 0; j < 4; ++j) {
        int idx = base + j;
        int d = (idx < n) ? a[idx] : 0;
        v[j] = s;  // exclusive within thread
        s += d;
    }
    sc[t] = s;
    __syncthreads();
    for (int off = 1; off < 256; off <<= 1) {
        int x = (t >= off) ? sc[t - off] : 0;
        __syncthreads();
        sc[t] += x;
        __syncthreads();
    }
    int excl = sc[t] - s;
    #pragma unroll
    for (int j = 0; j < 4; ++j) {
        int idx = base + j;
        if (idx < n) a[idx] = v[j] + excl;
    }
    if (t == 255) bsum[b] = sc[255];
}

// ---------------- tiny 1-block exclusive scan of block sums -----------------
__global__ __launch_bounds__(256) void k_scanb(int* __restrict__ a, int nb) {
    __shared__ int sc[256];
    int t = threadIdx.x;
    int v = (t < nb) ? a[t] : 0;
    sc[t] = v;
    __syncthreads();
    for (int off = 1; off < 256; off <<= 1) {
        int u = (t >= off) ? sc[t - off] : 0;
        __syncthreads();
        sc[t] += u;
        __syncthreads();
    }
    if (t < nb) a[t] = sc[t] - v;  // exclusive
}

// ---------------- level-1: bucket edges window-major (packed 32-bit) --------
__global__ __launch_bounds__(256) void k_bucket(const int* __restrict__ src,
                                                const int* __restrict__ dst,
                                                const int* __restrict__ hist_g,
                                                const int* __restrict__ bsum2,
                                                unsigned* __restrict__ eb, int E, int nw) {
    __shared__ int lcur[256];
    int b = blockIdx.x;
    for (int w = threadIdx.x; w < nw; w += 256) {
        int idx = w * NJ1 + b;
        lcur[w] = hist_g[idx] + bsum2[idx >> 10];
    }
    __syncthreads();
    int ch = (E + NJ1 - 1) / NJ1;
    int e0 = b * ch, e1 = min(e0 + ch, E);
    // 4 consecutive edges per thread per iter (int4 loads)
    for (int i = e0 + threadIdx.x * 4; i < e1; i += 1024) {
        if (i + 3 < e1) {
            int4 d = *(const int4*)(dst + i);
            int4 s = *(const int4*)(src + i);
            int p0 = atomicAdd(&lcur[d.x >> WB], 1);
            eb[p0] = ((unsigned)s.x << WB) | (unsigned)(d.x & (WSZ - 1));
            int p1 = atomicAdd(&lcur[d.y >> WB], 1);
            eb[p1] = ((unsigned)s.y << WB) | (unsigned)(d.y & (WSZ - 1));
            int p2 = atomicAdd(&lcur[d.z >> WB], 1);
            eb[p2] = ((unsigned)s.z << WB) | (unsigned)(d.z & (WSZ - 1));
            int p3 = atomicAdd(&lcur[d.w >> WB], 1);
            eb[p3] = ((unsigned)s.w << WB) | (unsigned)(d.w & (WSZ - 1));
        } else {
            for (int j = i; j < e1; ++j) {
                int d = dst[j];
                int pos = atomicAdd(&lcur[d >> WB], 1);
                eb[pos] = ((unsigned)src[j] << WB) | (unsigned)(d & (WSZ - 1));
            }
        }
    }
}

// ---------------- fused CSR: hist + scan + scatter + dinv + xs + cnt --------
__global__ __launch_bounds__(256) void k_csr(const unsigned* __restrict__ eb,
                                             const int* __restrict__ hist_g,
                                             const int* __restrict__ bsum2,
                                             const float* __restrict__ x,
                                             const int* __restrict__ batch,
                                             int* __restrict__ rowptr,
                                             int* __restrict__ csr_src,
                                             float* __restrict__ dinv,
                                             unsigned short* __restrict__ xs,
                                             int* __restrict__ cnt,
                                             int E, int nw, int N, int G) {
    __shared__ int h[WSZ];
    __shared__ int cur[WSZ];
    __shared__ int sc[256];
    __shared__ int cbin[32];
    const int w = blockIdx.x;
    const int t = threadIdx.x;
    h[t] = 0;
    h[t + 256] = 0;
    if (t < 32) cbin[t] = 0;
    __syncthreads();
    const int wi0 = w * NJ1;
    const int s0 = hist_g[wi0] + bsum2[wi0 >> 10];
    int s1;
    if (w + 1 < nw) {
        const int wi1 = (w + 1) * NJ1;
        s1 = hist_g[wi1] + bsum2[wi1 >> 10];
    } else {
        s1 = E;
    }
    // histogram pass: 4 consecutive eb entries per thread per iter
    for (int i = s0 + t * 4; i < s1; i += 1024) {
        if (i + 3 < s1) {
            uint4 e4 = *(const uint4*)(eb + i);
            atomicAdd(&h[e4.x & (WSZ - 1)], 1);
            atomicAdd(&h[e4.y & (WSZ - 1)], 1);
            atomicAdd(&h[e4.z & (WSZ - 1)], 1);
            atomicAdd(&h[e4.w & (WSZ - 1)], 1);
        } else {
            for (int j = i; j < s1; ++j) atomicAdd(&h[eb[j] & (WSZ - 1)], 1);
        }
    }
    __syncthreads();
    // pair-scan: thread t owns nodes 2t, 2t+1
    int h0 = h[2 * t], h1 = h[2 * t + 1];
    int ps = h0 + h1;
    sc[t] = ps;
    __syncthreads();
    for (int off = 1; off < 256; off <<= 1) {
        int xv = (t >= off) ? sc[t - off] : 0;
        __syncthreads();
        sc[t] += xv;
        __syncthreads();
    }
    int excl = sc[t] - ps;
    const int base = w << WB;
    int p0 = s0 + excl, p1 = p0 + h0;
    cur[2 * t] = p0;
    cur[2 * t + 1] = p1;
    int n0i = base + 2 * t, n1i = n0i + 1;
    const int g_lo = batch[base];
    float dv0 = 0.f, dv1 = 0.f;
    if (n0i < N) {
        rowptr[n0i] = p0;
        dv0 = rsqrtf((float)h0 + 1.0f);
        dinv[n0i] = dv0;
        int b0 = batch[n0i] - g_lo;
        if ((unsigned)b0 < 32u) atomicAdd(&cbin[b0], 1);
        else atomicAdd(&cnt[batch[n0i]], 1);
    }
    if (n1i < N) {
        rowptr[n1i] = p1;
        dv1 = rsqrtf((float)h1 + 1.0f);
        dinv[n1i] = dv1;
        int b1 = batch[n1i] - g_lo;
        if ((unsigned)b1 < 32u) atomicAdd(&cbin[b1], 1);
        else atomicAdd(&cnt[batch[n1i]], 1);
    }
    if (w == nw - 1 && t == 255) rowptr[N] = E;
    // xs rows (bf16, 32B)
    if (n0i < N) {
        #pragma unroll
        for (int k = 0; k < 9; ++k) xs[n0i * 16 + k] = f2bf(x[(size_t)n0i * 9 + k] * dv0);
        #pragma unroll
        for (int k = 9; k < 16; ++k) xs[n0i * 16 + k] = 0;
    }
    if (n1i < N) {
        #pragma unroll
        for (int k = 0; k < 9; ++k) xs[n1i * 16 + k] = f2bf(x[(size_t)n1i * 9 + k] * dv1);
        #pragma unroll
        for (int k = 9; k < 16; ++k) xs[n1i * 16 + k] = 0;
    }
    __syncthreads();
    if (t < 32 && cbin[t] > 0) {
        int g = g_lo + t;
        if (g < G) atomicAdd(&cnt[g], cbin[t]);
    }
    // scatter pass: 4 consecutive eb entries per thread per iter (L2-hot)
    for (int i = s0 + t * 4; i < s1; i += 1024) {
        if (i + 3 < s1) {
            uint4 e4 = *(const uint4*)(eb + i);
            int q0 = atomicAdd(&cur[e4.x & (WSZ - 1)], 1);
            csr_src[q0] = (int)(e4.x >> WB);
            int q1 = atomicAdd(&cur[e4.y & (WSZ - 1)], 1);
            csr_src[q1] = (int)(e4.y >> WB);
            int q2 = atomicAdd(&cur[e4.z & (WSZ - 1)], 1);
            csr_src[q2] = (int)(e4.z >> WB);
            int q3 = atomicAdd(&cur[e4.w & (WSZ - 1)], 1);
            csr_src[q3] = (int)(e4.w >> WB);
        } else {
            for (int j = i; j < s1; ++j) {
                unsigned ep = eb[j];
                int pos = atomicAdd(&cur[ep & (WSZ - 1)], 1);
                csr_src[pos] = (int)(ep >> WB);
            }
        }
    }
}

// ---------------- layer-1 agg: 2 lanes x uint4 per row, 16 edge slots -------
__global__ __launch_bounds__(256) void k_aggx(const unsigned short* __restrict__ xs,
                                              const int* __restrict__ rowptr,
                                              const int* __restrict__ csr_src,
                                              const float* __restrict__ dinv,
                                              unsigned short* __restrict__ xab, int N) {
    int wv = threadIdx.x >> 6;
    int n0 = blockIdx.x * 8 + wv * 2;
    if (n0 >= N) return;
    int lane = threadIdx.x & 63;
    int h = lane >> 5;
    int es = (lane >> 1) & 15;
    int o = lane & 1;
    int n = n0 + h;
    bool valid = (n < N);
    if (!valid) n = n0;
    const uint4* xs4 = (const uint4*)xs;  // row = 2 x uint4 (32 B)
    float a[8] = {0.f, 0.f, 0.f, 0.f, 0.f, 0.f, 0.f, 0.f};
    int s = rowptr[n], e = rowptr[n + 1];
    int i = s;
    while (i + 32 <= e) {
        int idx0 = csr_src[i + es];
        int idx1 = csr_src[i + 16 + es];
        uint4 u0 = xs4[(unsigned)idx0 * 2 + o];
        uint4 u1 = xs4[(unsigned)idx1 * 2 + o];
        addbf8(a, u0);
        addbf8(a, u1);
        i += 32;
    }
    if (i < e) {
        int k0 = i + es, k1 = i + 16 + es;
        float w0 = (k0 < e) ? 1.0f : 0.0f;
        float w1 = (k1 < e) ? 1.0f : 0.0f;
        int i0 = (k0 < e) ? k0 : (e - 1);
        int i1 = (k1 < e) ? k1 : (e - 1);
        int idx0 = csr_src[i0];
        int idx1 = csr_src[i1];
        uint4 u0 = xs4[(unsigned)idx0 * 2 + o];
        uint4 u1 = xs4[(unsigned)idx1 * 2 + o];
        addbf8m(a, u0, w0);
        addbf8m(a, u1, w1);
    }
    #pragma unroll
    for (int j = 0; j < 8; ++j) {
        a[j] += __shfl_xor(a[j], 2);
        a[j] += __shfl_xor(a[j], 4);
        a[j] += __shfl_xor(a[j], 8);
        a[j] += __shfl_xor(a[j], 16);
    }
    if (valid && es == 0) {
        uint4 u = xs4[(unsigned)n * 2 + o];  // self
        addbf8(a, u);
        float dv = dinv[n];
        uint4 st;
        st.x = (unsigned)f2bf(dv * a[0]) | ((unsigned)f2bf(dv * a[1]) << 16);
        st.y = (unsigned)f2bf(dv * a[2]) | ((unsigned)f2bf(dv * a[3]) << 16);
        st.z = (unsigned)f2bf(dv * a[4]) | ((unsigned)f2bf(dv * a[5]) << 16);
        st.w = (unsigned)f2bf(dv * a[6]) | ((unsigned)f2bf(dv * a[7]) << 16);
        *(uint4*)(xab + (size_t)n * 16 + 8 * o) = st;
    }
}

// ---------------- fused layer-1+layer-2 GEMM, W1t LDS-resident --------------
// 128 nodes/block (grid 782), 2 tiles/wave. W1t (32KB) staged to LDS with
// XOR row swizzle (byte ^ ((row&7)<<4)); Wint + bias in registers.
__global__ __launch_bounds__(256, 2) void k_gemm1(const unsigned short* __restrict__ xab,
                                                  const unsigned short* __restrict__ Wint,
                                                  const float* __restrict__ bin,
                                                  const unsigned short* __restrict__ Wt,
                                                  const float* __restrict__ dinv,
                                                  unsigned char* __restrict__ Out, int N) {
    __shared__ unsigned char Wl[32768];      // swizzled W1t
    __shared__ unsigned short H2[4][16 * LDA];
    const int tid = threadIdx.x;
    // cooperative stage: 2048 uint4, xor-swizzled rows (row = byte>>8)
    #pragma unroll
    for (int i2 = 0; i2 < 8; ++i2) {
        int i = tid + i2 * 256;
        uint4 v = ((const uint4*)Wt)[i];
        int b = i * 16;
        *(uint4*)(Wl + (b ^ (((b >> 8) & 7) << 4))) = v;
    }
    const int wave = tid >> 6, lane = tid & 63;
    const int m16 = lane & 15, q = lane >> 4;
    bf16x8 w1r[8];
    #pragma unroll
    for (int t = 0; t < 8; ++t)
        w1r[t] = *(const bf16x8*)(Wint + ((t * 16 + m16) * 32 + q * 8));
    float b1v[8];
    #pragma unroll
    for (int t = 0; t < 8; ++t) b1v[t] = bin[t * 16 + m16];
    __syncthreads();
    unsigned short* h2s = H2[wave];
    const unsigned swz = ((unsigned)(m16 & 7)) << 4;
    #pragma unroll
    for (int tile = 0; tile < 2; ++tile) {
        const int row0 = blockIdx.x * 128 + tile * 64 + wave * 16;
        int arow = row0 + m16;
        if (arow >= N) arow = N - 1;
        bf16x8 a1;
        if (q < 2) a1 = *(const bf16x8*)(xab + (size_t)arow * 16 + q * 8);
        else a1 = (bf16x8){0, 0, 0, 0, 0, 0, 0, 0};
        f32x4 acc1[8];
        #pragma unroll
        for (int t = 0; t < 8; ++t) acc1[t] = (f32x4){0.f, 0.f, 0.f, 0.f};
        #pragma unroll
        for (int t = 0; t < 8; ++t)
            acc1[t] = __builtin_amdgcn_mfma_f32_16x16x32_bf16(a1, w1r[t], acc1[t], 0, 0, 0);
        #pragma unroll
        for (int t = 0; t < 8; ++t) {
            #pragma unroll
            for (int r = 0; r < 4; ++r)
                h2s[(q * 4 + r) * LDA + t * 16 + m16] = f2bf(ftanh(acc1[t][r] + b1v[t]));
        }
        const unsigned short* h2row = h2s + m16 * LDA + q * 8;
        f32x4 acc[8];
        #pragma unroll
        for (int t = 0; t < 8; ++t) acc[t] = (f32x4){0.f, 0.f, 0.f, 0.f};
        #pragma unroll
        for (int kc = 0; kc < 4; ++kc) {
            bf16x8 af = *(const bf16x8*)(h2row + kc * 32);
            #pragma unroll
            for (int t = 0; t < 8; ++t) {
                unsigned wb = (unsigned)((t * 16 + m16) << 8) + (unsigned)(kc * 64 + q * 16);
                bf16x8 wr = *(const bf16x8*)(Wl + (wb ^ swz));
                acc[t] = __builtin_amdgcn_mfma_f32_16x16x32_bf16(af, wr, acc[t], 0, 0, 0);
            }
        }
        float dv[4];
        #pragma unroll
        for (int r = 0; r < 4; ++r) {
            int gr = row0 + q * 4 + r;
            dv[r] = (gr < N) ? dinv[gr] : 0.0f;
        }
        #pragma unroll
        for (int t = 0; t < 8; ++t) {
            #pragma unroll
            for (int r = 0; r < 4; ++r) {
                int gr = row0 + q * 4 + r;
                if (gr < N) Out[(size_t)gr * U + t * 16 + m16] = f2fp8(acc[t][r] * dv[r]);
            }
        }
    }
}

// ---------------- layer-3 GEMM, Wt LDS-resident (128 nodes/blk) -------------
__global__ __launch_bounds__(256, 2) void k_gemm2(const unsigned short* __restrict__ A,
                                                  const unsigned short* __restrict__ Wt,
                                                  const float* __restrict__ dinv,
                                                  unsigned char* __restrict__ Out, int N) {
    __shared__ unsigned char Wl[32768];
    const int tid = threadIdx.x;
    #pragma unroll
    for (int i2 = 0; i2 < 8; ++i2) {
        int i = tid + i2 * 256;
        uint4 v = ((const uint4*)Wt)[i];
        int b = i * 16;
        *(uint4*)(Wl + (b ^ (((b >> 8) & 7) << 4))) = v;
    }
    const int wave = tid >> 6, lane = tid & 63;
    const int m16 = lane & 15, q = lane >> 4;
    __syncthreads();
    const unsigned swz = ((unsigned)(m16 & 7)) << 4;
    #pragma unroll
    for (int tile = 0; tile < 2; ++tile) {
        const int row0 = blockIdx.x * 128 + tile * 64 + wave * 16;
        int ar = row0 + m16;
        if (ar >= N) ar = N - 1;
        const bf16x8* arow = (const bf16x8*)(A + (size_t)ar * U + q * 8);
        bf16x8 a[4];
        #pragma unroll
        for (int kc = 0; kc < 4; ++kc) a[kc] = arow[kc * 4];
        f32x4 acc[8];
        #pragma unroll
        for (int t = 0; t < 8; ++t) acc[t] = (f32x4){0.f, 0.f, 0.f, 0.f};
        #pragma unroll
        for (int kc = 0; kc < 4; ++kc) {
            #pragma unroll
            for (int t = 0; t < 8; ++t) {
                unsigned wb = (unsigned)((t * 16 + m16) << 8) + (unsigned)(kc * 64 + q * 16);
                bf16x8 wr = *(const bf16x8*)(Wl + (wb ^ swz));
                acc[t] = __builtin_amdgcn_mfma_f32_16x16x32_bf16(a[kc], wr, acc[t], 0, 0, 0);
            }
        }
        float dv[4];
        #pragma unroll
        for (int r = 0; r < 4; ++r) {
            int gr = row0 + q * 4 + r;
            dv[r] = (gr < N) ? dinv[gr] : 0.0f;
        }
        #pragma unroll
        for (int t = 0; t < 8; ++t) {
            #pragma unroll
            for (int r = 0; r < 4; ++r) {
                int gr = row0 + q * 4 + r;
                if (gr < N) Out[(size_t)gr * U + t * 16 + m16] = f2fp8(acc[t][r] * dv[r]);
            }
        }
    }
}

// ---------------- aggregation (fp8 table): uint4 rows, half-wave per node ---
__global__ __launch_bounds__(256) void k_aggb(const unsigned char* __restrict__ Tb,
                                              const int* __restrict__ rowptr,
                                              const int* __restrict__ csr_src,
                                              const float* __restrict__ dinv,
                                              const float* __restrict__ bias,
                                              unsigned short* __restrict__ Out, int N) {
    int wv = threadIdx.x >> 6;
    int n0 = blockIdx.x * 8 + wv * 2;
    if (n0 >= N) return;
    int lane = threadIdx.x & 63;
    int h = lane >> 5;
    int q = (lane >> 3) & 3;
    int o = lane & 7;
    int n = n0 + h;
    bool valid = (n < N);
    if (!valid) n = n0;
    const char* Tc = (const char*)Tb;
    const unsigned loff = (unsigned)o << 4;  // byte offset of my uint4 in row
    f32x2 acc[8];
    #pragma unroll
    for (int j = 0; j < 8; ++j) acc[j] = (f32x2){0.f, 0.f};
    int s = rowptr[n], e = rowptr[n + 1];
    int i = s;
    while (i + 16 <= e) {
        int idx[4];
        #pragma unroll
        for (int g2 = 0; g2 < 4; ++g2) idx[g2] = csr_src[i + g2 * 4 + q];
        uint4 u[4];
        #pragma unroll
        for (int g2 = 0; g2 < 4; ++g2)
            u[g2] = *(const uint4*)(Tc + (((unsigned)idx[g2] << 7) + loff));
        #pragma unroll
        for (int g2 = 0; g2 < 4; ++g2) acc16(acc, u[g2]);
        i += 16;
    }
    if (i < e) {
        int ii[4];
        float w[4];
        #pragma unroll
        for (int g2 = 0; g2 < 4; ++g2) {
            int k = i + g2 * 4 + q;
            w[g2] = (k < e) ? 1.0f : 0.0f;
            ii[g2] = (k < e) ? k : (e - 1);
        }
        int idx[4];
        #pragma unroll
        for (int g2 = 0; g2 < 4; ++g2) idx[g2] = csr_src[ii[g2]];
        uint4 u[4];
        #pragma unroll
        for (int g2 = 0; g2 < 4; ++g2)
            u[g2] = *(const uint4*)(Tc + (((unsigned)idx[g2] << 7) + loff));
        #pragma unroll
        for (int g2 = 0; g2 < 4; ++g2) acc16m(acc, u[g2], w[g2]);
    }
    float* af = (float*)acc;
    #pragma unroll
    for (int j = 0; j < 16; ++j) {
        af[j] += __shfl_xor(af[j], 8);
        af[j] += __shfl_xor(af[j], 16);
    }
    f32x2 vA = (q < 2) ? ((q == 0) ? acc[0] : acc[2]) : ((q == 2) ? acc[4] : acc[6]);
    f32x2 vB = (q < 2) ? ((q == 0) ? acc[1] : acc[3]) : ((q == 2) ? acc[5] : acc[7]);
    int f = 16 * o + 4 * q;
    float4 bb = *(const float4*)&bias[f];
    float dv = dinv[n];
    unsigned selfu = *(const unsigned*)(Tc + ((unsigned)n << 7) + f);
    f32x2 s01 = __builtin_amdgcn_cvt_pk_f32_fp8(selfu, false);
    f32x2 s23 = __builtin_amdgcn_cvt_pk_f32_fp8(selfu, true);
    float o0 = ftanh(dv * (vA[0] + s01[0]) + bb.x);
    float o1 = ftanh(dv * (vA[1] + s01[1]) + bb.y);
    float o2 = ftanh(dv * (vB[0] + s23[0]) + bb.z);
    float o3 = ftanh(dv * (vB[1] + s23[1]) + bb.w);
    if (valid) {
        uint2 st;
        st.x = (unsigned)f2bf(o0) | ((unsigned)f2bf(o1) << 16);
        st.y = (unsigned)f2bf(o2) | ((unsigned)f2bf(o3) << 16);
        *(uint2*)((char*)Out + ((size_t)n << 8) + ((unsigned)f << 1)) = st;
    }
}

// ---------------- fused MFMA MLP head v2 (as R9) ----------------
__global__ __launch_bounds__(256, 2) void k_mlp(const unsigned short* __restrict__ H,
                                                const unsigned short* __restrict__ Wf1t,
                                                const float* __restrict__ bf1,
                                                const unsigned short* __restrict__ Wf2t,
                                                const float* __restrict__ bf2,
                                                const float* __restrict__ Wf3,
                                                const float* __restrict__ bf3,
                                                const int* __restrict__ batch,
                                                float* __restrict__ util_sum,
                                                int N, int G) {
    __shared__ unsigned short H2[4][16 * LDA];  // per-wave transpose slice
    __shared__ float gsum[8];
    const int tid = threadIdx.x;
    if (tid < 8) gsum[tid] = 0.0f;
    const int wave = tid >> 6, lane = tid & 63;
    const int m16 = lane & 15, q = lane >> 4;
    const int blk0 = blockIdx.x * 256;
    const int g0 = batch[min(blk0, N - 1)];
    bf16x8 w1[4][8], w2[4][2];
    #pragma unroll
    for (int kc = 0; kc < 4; ++kc) {
        #pragma unroll
        for (int t = 0; t < 8; ++t)
            w1[kc][t] = *(const bf16x8*)(Wf1t + ((t * 16 + m16) * 128 + kc * 32 + q * 8));
        #pragma unroll
        for (int t = 0; t < 2; ++t)
            w2[kc][t] = *(const bf16x8*)(Wf2t + ((t * 16 + m16) * 128 + kc * 32 + q * 8));
    }
    float b1v[8];
    #pragma unroll
    for (int t = 0; t < 8; ++t) b1v[t] = bf1[t * 16 + m16];
    const float b2lo = bf2[m16], b2hi = bf2[m16 + 16];
    const float w3lo = Wf3[m16], w3hi = Wf3[m16 + 16];
    const float bf3v = bf3[0];
    __syncthreads();  // gsum init visible before tile atomics
    unsigned short* h2s = H2[wave];
    const int wbase = blk0 + wave * 64;
    bf16x8 a[4];
    {
        int ar = wbase + m16;
        if (ar >= N) ar = N - 1;
        const bf16x8* arow = (const bf16x8*)(H + (size_t)ar * U + q * 8);
        #pragma unroll
        for (int kc = 0; kc < 4; ++kc) a[kc] = arow[kc * 4];
    }
    for (int tile = 0; tile < 4; ++tile) {
        const int row0 = wbase + tile * 16;
        bf16x8 an[4];
        if (tile < 3) {
            int ar = row0 + 16 + m16;
            if (ar >= N) ar = N - 1;
            const bf16x8* arow = (const bf16x8*)(H + (size_t)ar * U + q * 8);
            #pragma unroll
            for (int kc = 0; kc < 4; ++kc) an[kc] = arow[kc * 4];
        }
        f32x4 acc[8];
        #pragma unroll
        for (int t = 0; t < 8; ++t) acc[t] = (f32x4){0.f, 0.f, 0.f, 0.f};
        #pragma unroll
        for (int kc = 0; kc < 4; ++kc) {
            #pragma unroll
            for (int t = 0; t < 8; ++t)
                acc[t] = __builtin_amdgcn_mfma_f32_16x16x32_bf16(a[kc], w1[kc][t], acc[t], 0, 0, 0);
        }
        #pragma unroll
        for (int t = 0; t < 8; ++t) {
            #pragma unroll
            for (int r = 0; r < 4; ++r) {
                int lr = q * 4 + r;
                h2s[lr * LDA + t * 16 + m16] = f2bf(ftanh(acc[t][r] + b1v[t]));
            }
        }
        f32x4 acc2[2];
        acc2[0] = (f32x4){0.f, 0.f, 0.f, 0.f};
        acc2[1] = (f32x4){0.f, 0.f, 0.f, 0.f};
        const unsigned short* h2row = h2s + m16 * LDA + q * 8;
        #pragma unroll
        for (int kc = 0; kc < 4; ++kc) {
            bf16x8 af = *(const bf16x8*)(h2row + kc * 32);
            #pragma unroll
            for (int t = 0; t < 2; ++t)
                acc2[t] = __builtin_amdgcn_mfma_f32_16x16x32_bf16(af, w2[kc][t], acc2[t], 0, 0, 0);
        }
        #pragma unroll
        for (int r = 0; r < 4; ++r) {
            float t0 = ftanh(acc2[0][r] + b2lo);
            float t1 = ftanh(acc2[1][r] + b2hi);
            float v = t0 * w3lo + t1 * w3hi;
            v += __shfl_xor(v, 1);
            v += __shfl_xor(v, 2);
            v += __shfl_xor(v, 4);
            v += __shfl_xor(v, 8);
            if (m16 == 0) {
                int n = row0 + q * 4 + r;
                if (n < N) atomicAdd(&gsum[batch[n] - g0], v + bf3v);
            }
        }
        #pragma unroll
        for (int kc = 0; kc < 4; ++kc) a[kc] = an[kc];
    }
    __syncthreads();
    if (tid < 8) {
        int g = g0 + tid;
        if (g < G) {
            float s = gsum[tid];
            if (s != 0.0f) atomicAdd(&util_sum[g], s);
        }
    }
}

// ---------------- fused output: util + pair sigmoid ----------------
__global__ void k_out(const float* __restrict__ us, const int* __restrict__ cnt,
                      const int* __restrict__ ia, const int* __restrict__ ib,
                      float* __restrict__ out, int P, int G) {
    int t = blockIdx.x * 256 + threadIdx.x;
    if (t < G) out[P + t] = us[t] / fmaxf((float)cnt[t], 1.0f);
    if (t < P) {
        int a = ia[t], b = ib[t];
        float ua = us[a] / fmaxf((float)cnt[a], 1.0f);
        float ub = us[b] / fmaxf((float)cnt[b], 1.0f);
        out[t] = 1.0f / (1.0f + expf(-(ub - ua)));
    }
}

extern "C" void kernel_launch(void* const* d_in, const int* in_sizes, int n_in,
                              void* d_out, int out_size, void* d_ws, size_t ws_size,
                              hipStream_t stream) {
    const float* x     = (const float*)d_in[0];
    const int*   eidx  = (const int*)d_in[1];
    const int*   batch = (const int*)d_in[2];
    const int*   idx_a = (const int*)d_in[3];
    const int*   idx_b = (const int*)d_in[4];
    const float* W_in  = (const float*)d_in[5];
    const float* b_in  = (const float*)d_in[6];
    const float* W1    = (const float*)d_in[7];
    const float* b1    = (const float*)d_in[8];
    const float* W2    = (const float*)d_in[9];
    const float* b2    = (const float*)d_in[10];
    const float* Wf1   = (const float*)d_in[11];
    const float* bf1   = (const float*)d_in[12];
    const float* Wf2   = (const float*)d_in[13];
    const float* bf2   = (const float*)d_in[14];
    const float* Wf3   = (const float*)d_in[15];
    const float* bf3   = (const float*)d_in[16];
    float* out = (float*)d_out;

    const int N = in_sizes[0] / 9;
    const int E = in_sizes[1] / 2;
    const int P = in_sizes[3];
    const int G = out_size - P;

    const int* src = eidx;
    const int* dst = eidx + E;

    const int nw = (N + WSZ - 1) >> WB;  // level-2 windows (196 for N=100k)
    const int nh = nw * NJ1;             // hist_g size
    const int nbh = (nh + 1023) / 1024;  // scan blocks for hist_g

    // ---- workspace carve-out ----
    char* ws = (char*)d_ws;
    size_t off = 0;
    auto take = [&](size_t bytes) -> void* {
        void* p = ws + off;
        off = (off + bytes + 255) & ~(size_t)255;
        return p;
    };
    float* dinv     = (float*)take((size_t)N * 4);
    int*   rowptr   = (int*)  take((size_t)(N + 1) * 4);
    int*   bsum2    = (int*)  take(256 * 4);
    int*   hist_g   = (int*)  take((size_t)nh * 4);
    unsigned* eb    = (unsigned*)take((size_t)E * 4);   // packed (src<<9)|dloc
    int*   csr_src  = (int*)  take((size_t)E * 4);
    unsigned short* xs  = (unsigned short*)take((size_t)N * 16 * 2);  // bf16 32B rows
    unsigned short* xab = (unsigned short*)take((size_t)N * 16 * 2);  // bf16 A-frag rows
    unsigned short* bufA = (unsigned short*)take((size_t)N * U * 2);  // bf16 acts
    unsigned char*  Tb   = (unsigned char*) take((size_t)N * U);      // fp8 table
    unsigned short* Wint = (unsigned short*)take(128 * 32 * 2);       // W_in^T pad K=32
    unsigned short* W1t  = (unsigned short*)take(128 * 128 * 2);
    unsigned short* W2t  = (unsigned short*)take(128 * 128 * 2);
    unsigned short* Wf1t = (unsigned short*)take(128 * 128 * 2);
    unsigned short* Wf2t = (unsigned short*)take(32 * 128 * 2);
    // zero-region: util_sum + cnt contiguous, single memset
    float* util_sum = (float*)take((size_t)G * 8);
    int*   cnt      = (int*)(util_sum + G);
    (void)ws_size;

    hipMemsetAsync(util_sum, 0, (size_t)G * 8, stream);

    // ---- CSR build: two-level counting sort, fused window CSR ----
    k_hist1<<<NJ1, 256, 0, stream>>>(dst, hist_g, W_in, W1, W2, Wf1, Wf2,
                                     Wint, W1t, W2t, Wf1t, Wf2t, E, nw);
    k_escan1<<<nbh, 256, 0, stream>>>(hist_g, bsum2, nh);
    k_scanb<<<1, 256, 0, stream>>>(bsum2, nbh);
    k_bucket<<<NJ1, 256, 0, stream>>>(src, dst, hist_g, bsum2, eb, E, nw);
    k_csr<<<nw, 256, 0, stream>>>(eb, hist_g, bsum2, x, batch, rowptr, csr_src,
                                  dinv, xs, cnt, E, nw, N, G);

    const int gemmGrid = (N + 127) / 128;  // 128 nodes/block (grid 782)
    const int aggGrid = (N + 7) / 8;       // 2 nodes/wave, 8 nodes/block

    // ---- GCN layer 1 agg + fused layer-1/layer-2 GEMM -> fp8 ----
    k_aggx<<<aggGrid, 256, 0, stream>>>(xs, rowptr, csr_src, dinv, xab, N);
    k_gemm1<<<gemmGrid, 256, 0, stream>>>(xab, Wint, b_in, W1t, dinv, Tb, N);
    k_aggb<<<aggGrid, 256, 0, stream>>>(Tb, rowptr, csr_src, dinv, b1, bufA, N);
    // ---- GCN layer 3 ----
    k_gemm2<<<gemmGrid, 256, 0, stream>>>(bufA, W2t, dinv, Tb, N);
    k_aggb<<<aggGrid, 256, 0, stream>>>(Tb, rowptr, csr_src, dinv, b2, bufA, N);

    // ---- MLP head + pooled sums (256 nodes/block) ----
    k_mlp<<<(N + 255) / 256, 256, 0, stream>>>(bufA, Wf1t, bf1, Wf2t, bf2, Wf3, bf3,
                                               batch, util_sum, N, G);

    // ---- fused util + pairs ----
    int mx = (P > G ? P : G);
    k_out<<<(mx + 255) / 256, 256, 0, stream>>>(util_sum, cnt, idx_a, idx_b, out, P, G);
}

// Round 14
// 310.870 us; speedup vs baseline: 1.1381x; 1.0012x over previous
//
#include <hip/hip_runtime.h>
#include <hip/hip_bf16.h>
#include <math.h>

// ---------------------------------------------------------------------------
// RankGNN R28: R27 (best, 311us) + occupancy bump on the LDS-weight gemm
// kernels only: k_gemm1 __launch_bounds__(256,3) (49KB LDS -> 3 blocks/CU),
// k_gemm2 __launch_bounds__(256,4) (32KB -> 4 blocks/CU). Everything else
// bit-identical to R27. aggb remains at its compulsory-fetch wall.
// ---------------------------------------------------------------------------

#define U 128
#define LDA 136    // LDS row stride in bf16 elems (128 + 8 pad)
#define WB 9       // log2(window) = 512 nodes per level-2 window
#define WSZ 512
#define NJ1 512    // level-1 blocks (edge chunks)

typedef __attribute__((ext_vector_type(8))) short bf16x8;
typedef __attribute__((ext_vector_type(4))) float f32x4;
typedef __attribute__((ext_vector_type(2))) float f32x2;

__device__ __forceinline__ unsigned short f2bf(float f) {
    unsigned u = __float_as_uint(f);
    unsigned r = (u + 0x7fffu + ((u >> 16) & 1u)) >> 16;  // RNE
    return (unsigned short)r;
}
__device__ __forceinline__ float bf2f(unsigned short u) {
    return __uint_as_float((unsigned)u << 16);
}
__device__ __forceinline__ unsigned char f2fp8(float v) {
    return (unsigned char)(__builtin_amdgcn_cvt_pk_fp8_f32(v, v, 0, false) & 0xff);
}
__device__ __forceinline__ float ftanh(float x) {
    float cx = fminf(fmaxf(x, -9.0f), 9.0f);
    float t = __expf(2.0f * cx);
    return (t - 1.0f) / (t + 1.0f);
}
// unpack uint4 = 16 fp8 feats into 8 f32x2 accumulators (v_pk_add_f32)
__device__ __forceinline__ void acc16(f32x2* a, uint4 u) {
    a[0] += __builtin_amdgcn_cvt_pk_f32_fp8(u.x, false);
    a[1] += __builtin_amdgcn_cvt_pk_f32_fp8(u.x, true);
    a[2] += __builtin_amdgcn_cvt_pk_f32_fp8(u.y, false);
    a[3] += __builtin_amdgcn_cvt_pk_f32_fp8(u.y, true);
    a[4] += __builtin_amdgcn_cvt_pk_f32_fp8(u.z, false);
    a[5] += __builtin_amdgcn_cvt_pk_f32_fp8(u.z, true);
    a[6] += __builtin_amdgcn_cvt_pk_f32_fp8(u.w, false);
    a[7] += __builtin_amdgcn_cvt_pk_f32_fp8(u.w, true);
}
__device__ __forceinline__ void acc16m(f32x2* a, uint4 u, float m) {
    f32x2 mm = (f32x2){m, m};
    a[0] += mm * __builtin_amdgcn_cvt_pk_f32_fp8(u.x, false);
    a[1] += mm * __builtin_amdgcn_cvt_pk_f32_fp8(u.x, true);
    a[2] += mm * __builtin_amdgcn_cvt_pk_f32_fp8(u.y, false);
    a[3] += mm * __builtin_amdgcn_cvt_pk_f32_fp8(u.y, true);
    a[4] += mm * __builtin_amdgcn_cvt_pk_f32_fp8(u.z, false);
    a[5] += mm * __builtin_amdgcn_cvt_pk_f32_fp8(u.z, true);
    a[6] += mm * __builtin_amdgcn_cvt_pk_f32_fp8(u.w, false);
    a[7] += mm * __builtin_amdgcn_cvt_pk_f32_fp8(u.w, true);
}
// unpack uint2 = 4 bf16 feats, accumulate (shift/mask only)
__device__ __forceinline__ void addbf4(float* a, uint2 u) {
    a[0] += __uint_as_float(u.x << 16);
    a[1] += __uint_as_float(u.x & 0xffff0000u);
    a[2] += __uint_as_float(u.y << 16);
    a[3] += __uint_as_float(u.y & 0xffff0000u);
}
__device__ __forceinline__ void addbf8(float* a, uint4 u) {
    addbf4(a, make_uint2(u.x, u.y));
    addbf4(a + 4, make_uint2(u.z, u.w));
}
__device__ __forceinline__ void addbf8m(float* a, uint4 u, float w) {
    a[0] += w * __uint_as_float(u.x << 16);
    a[1] += w * __uint_as_float(u.x & 0xffff0000u);
    a[2] += w * __uint_as_float(u.y << 16);
    a[3] += w * __uint_as_float(u.y & 0xffff0000u);
    a[4] += w * __uint_as_float(u.z << 16);
    a[5] += w * __uint_as_float(u.z & 0xffff0000u);
    a[6] += w * __uint_as_float(u.w << 16);
    a[7] += w * __uint_as_float(u.w & 0xffff0000u);
}

// ---------------- level-1: window histogram + weight transposes -------------
__global__ __launch_bounds__(256) void k_hist1(const int* __restrict__ dst,
                                               int* __restrict__ hist_g,
                                               const float* __restrict__ W_in,
                                               const float* __restrict__ W1,
                                               const float* __restrict__ W2,
                                               const float* __restrict__ Wf1,
                                               const float* __restrict__ Wf2,
                                               unsigned short* __restrict__ Wint,
                                               unsigned short* __restrict__ W1t,
                                               unsigned short* __restrict__ W2t,
                                               unsigned short* __restrict__ Wf1t,
                                               unsigned short* __restrict__ Wf2t,
                                               int E, int nw) {
    __shared__ int h[256];  // nw <= 256
    int b = blockIdx.x;
    // fold former k_prep weight transposes (independent work)
    int gid = b * 256 + threadIdx.x;
    if (gid < 16384) {
        int n = gid >> 7, k = gid & 127;
        W1t[n * 128 + k] = f2bf(W1[k * 128 + n]);
        Wf1t[n * 128 + k] = f2bf(Wf1[k * 128 + n]);
    } else if (gid < 32768) {
        int i = gid - 16384, n = i >> 7, k = i & 127;
        W2t[n * 128 + k] = f2bf(W2[k * 128 + n]);
    } else if (gid < 36864) {
        int i = gid - 32768, n = i >> 7, k = i & 127;
        Wf2t[n * 128 + k] = f2bf(Wf2[k * 32 + n]);
    } else if (gid < 40960) {
        int i = gid - 36864, c = i >> 5, k = i & 31;  // W_int[c][k], K padded
        Wint[c * 32 + k] = (k < 9) ? f2bf(W_in[k * 128 + c]) : (unsigned short)0;
    }
    for (int i = threadIdx.x; i < nw; i += 256) h[i] = 0;
    __syncthreads();
    int ch = (E + NJ1 - 1) / NJ1;
    int e0 = b * ch, e1 = min(e0 + ch, E);
    // 4 consecutive edges per thread per iter (int4 loads)
    for (int i = e0 + threadIdx.x * 4; i < e1; i += 1024) {
        if (i + 3 < e1) {
            int4 d = *(const int4*)(dst + i);
            atomicAdd(&h[d.x >> WB], 1);
            atomicAdd(&h[d.y >> WB], 1);
            atomicAdd(&h[d.z >> WB], 1);
            atomicAdd(&h[d.w >> WB], 1);
        } else {
            for (int j = i; j < e1; ++j) atomicAdd(&h[dst[j] >> WB], 1);
        }
    }
    __syncthreads();
    for (int w = threadIdx.x; w < nw; w += 256) hist_g[w * NJ1 + b] = h[w];
}

// ---------------- local exclusive scan (in place) + block sums --------------
__global__ __launch_bounds__(256) void k_escan1(int* __restrict__ a,
                                                int* __restrict__ bsum, int n) {
    __shared__ int sc[256];
    int t = threadIdx.x, b = blockIdx.x;
    int base = b * 1024 + t * 4;
    int v[4];
    int s = 0;
    #pragma unroll
    for (int j = 0; j < 4; ++j) {
        int idx = base + j;
        int d = (idx < n) ? a[idx] : 0;
        v[j] = s;  // exclusive within thread
        s += d;
    }
    sc[t] = s;
    __syncthreads();
    for (int off = 1; off < 256; off <<= 1) {
        int x = (t >= off) ? sc[t - off] : 0;
        __syncthreads();
        sc[t] += x;
        __syncthreads();
    }
    int excl = sc[t] - s;
    #pragma unroll
    for (int j = 0; j < 4; ++j) {
        int idx = base + j;
        if (idx < n) a[idx] = v[j] + excl;
    }
    if (t == 255) bsum[b] = sc[255];
}

// ---------------- tiny 1-block exclusive scan of block sums -----------------
__global__ __launch_bounds__(256) void k_scanb(int* __restrict__ a, int nb) {
    __shared__ int sc[256];
    int t = threadIdx.x;
    int v = (t < nb) ? a[t] : 0;
    sc[t] = v;
    __syncthreads();
    for (int off = 1; off < 256; off <<= 1) {
        int u = (t >= off) ? sc[t - off] : 0;
        __syncthreads();
        sc[t] += u;
        __syncthreads();
    }
    if (t < nb) a[t] = sc[t] - v;  // exclusive
}

// ---------------- level-1: bucket edges window-major (packed 32-bit) --------
__global__ __launch_bounds__(256) void k_bucket(const int* __restrict__ src,
                                                const int* __restrict__ dst,
                                                const int* __restrict__ hist_g,
                                                const int* __restrict__ bsum2,
                                                unsigned* __restrict__ eb, int E, int nw) {
    __shared__ int lcur[256];
    int b = blockIdx.x;
    for (int w = threadIdx.x; w < nw; w += 256) {
        int idx = w * NJ1 + b;
        lcur[w] = hist_g[idx] + bsum2[idx >> 10];
    }
    __syncthreads();
    int ch = (E + NJ1 - 1) / NJ1;
    int e0 = b * ch, e1 = min(e0 + ch, E);
    // 4 consecutive edges per thread per iter (int4 loads)
    for (int i = e0 + threadIdx.x * 4; i < e1; i += 1024) {
        if (i + 3 < e1) {
            int4 d = *(const int4*)(dst + i);
            int4 s = *(const int4*)(src + i);
            int p0 = atomicAdd(&lcur[d.x >> WB], 1);
            eb[p0] = ((unsigned)s.x << WB) | (unsigned)(d.x & (WSZ - 1));
            int p1 = atomicAdd(&lcur[d.y >> WB], 1);
            eb[p1] = ((unsigned)s.y << WB) | (unsigned)(d.y & (WSZ - 1));
            int p2 = atomicAdd(&lcur[d.z >> WB], 1);
            eb[p2] = ((unsigned)s.z << WB) | (unsigned)(d.z & (WSZ - 1));
            int p3 = atomicAdd(&lcur[d.w >> WB], 1);
            eb[p3] = ((unsigned)s.w << WB) | (unsigned)(d.w & (WSZ - 1));
        } else {
            for (int j = i; j < e1; ++j) {
                int d = dst[j];
                int pos = atomicAdd(&lcur[d >> WB], 1);
                eb[pos] = ((unsigned)src[j] << WB) | (unsigned)(d & (WSZ - 1));
            }
        }
    }
}

// ---------------- fused CSR: hist + scan + scatter + dinv + xs + cnt --------
__global__ __launch_bounds__(256) void k_csr(const unsigned* __restrict__ eb,
                                             const int* __restrict__ hist_g,
                                             const int* __restrict__ bsum2,
                                             const float* __restrict__ x,
                                             const int* __restrict__ batch,
                                             int* __restrict__ rowptr,
                                             int* __restrict__ csr_src,
                                             float* __restrict__ dinv,
                                             unsigned short* __restrict__ xs,
                                             int* __restrict__ cnt,
                                             int E, int nw, int N, int G) {
    __shared__ int h[WSZ];
    __shared__ int cur[WSZ];
    __shared__ int sc[256];
    __shared__ int cbin[32];
    const int w = blockIdx.x;
    const int t = threadIdx.x;
    h[t] = 0;
    h[t + 256] = 0;
    if (t < 32) cbin[t] = 0;
    __syncthreads();
    const int wi0 = w * NJ1;
    const int s0 = hist_g[wi0] + bsum2[wi0 >> 10];
    int s1;
    if (w + 1 < nw) {
        const int wi1 = (w + 1) * NJ1;
        s1 = hist_g[wi1] + bsum2[wi1 >> 10];
    } else {
        s1 = E;
    }
    // histogram pass: 4 consecutive eb entries per thread per iter
    for (int i = s0 + t * 4; i < s1; i += 1024) {
        if (i + 3 < s1) {
            uint4 e4 = *(const uint4*)(eb + i);
            atomicAdd(&h[e4.x & (WSZ - 1)], 1);
            atomicAdd(&h[e4.y & (WSZ - 1)], 1);
            atomicAdd(&h[e4.z & (WSZ - 1)], 1);
            atomicAdd(&h[e4.w & (WSZ - 1)], 1);
        } else {
            for (int j = i; j < s1; ++j) atomicAdd(&h[eb[j] & (WSZ - 1)], 1);
        }
    }
    __syncthreads();
    // pair-scan: thread t owns nodes 2t, 2t+1
    int h0 = h[2 * t], h1 = h[2 * t + 1];
    int ps = h0 + h1;
    sc[t] = ps;
    __syncthreads();
    for (int off = 1; off < 256; off <<= 1) {
        int xv = (t >= off) ? sc[t - off] : 0;
        __syncthreads();
        sc[t] += xv;
        __syncthreads();
    }
    int excl = sc[t] - ps;
    const int base = w << WB;
    int p0 = s0 + excl, p1 = p0 + h0;
    cur[2 * t] = p0;
    cur[2 * t + 1] = p1;
    int n0i = base + 2 * t, n1i = n0i + 1;
    const int g_lo = batch[base];
    float dv0 = 0.f, dv1 = 0.f;
    if (n0i < N) {
        rowptr[n0i] = p0;
        dv0 = rsqrtf((float)h0 + 1.0f);
        dinv[n0i] = dv0;
        int b0 = batch[n0i] - g_lo;
        if ((unsigned)b0 < 32u) atomicAdd(&cbin[b0], 1);
        else atomicAdd(&cnt[batch[n0i]], 1);
    }
    if (n1i < N) {
        rowptr[n1i] = p1;
        dv1 = rsqrtf((float)h1 + 1.0f);
        dinv[n1i] = dv1;
        int b1 = batch[n1i] - g_lo;
        if ((unsigned)b1 < 32u) atomicAdd(&cbin[b1], 1);
        else atomicAdd(&cnt[batch[n1i]], 1);
    }
    if (w == nw - 1 && t == 255) rowptr[N] = E;
    // xs rows (bf16, 32B)
    if (n0i < N) {
        #pragma unroll
        for (int k = 0; k < 9; ++k) xs[n0i * 16 + k] = f2bf(x[(size_t)n0i * 9 + k] * dv0);
        #pragma unroll
        for (int k = 9; k < 16; ++k) xs[n0i * 16 + k] = 0;
    }
    if (n1i < N) {
        #pragma unroll
        for (int k = 0; k < 9; ++k) xs[n1i * 16 + k] = f2bf(x[(size_t)n1i * 9 + k] * dv1);
        #pragma unroll
        for (int k = 9; k < 16; ++k) xs[n1i * 16 + k] = 0;
    }
    __syncthreads();
    if (t < 32 && cbin[t] > 0) {
        int g = g_lo + t;
        if (g < G) atomicAdd(&cnt[g], cbin[t]);
    }
    // scatter pass: 4 consecutive eb entries per thread per iter (L2-hot)
    for (int i = s0 + t * 4; i < s1; i += 1024) {
        if (i + 3 < s1) {
            uint4 e4 = *(const uint4*)(eb + i);
            int q0 = atomicAdd(&cur[e4.x & (WSZ - 1)], 1);
            csr_src[q0] = (int)(e4.x >> WB);
            int q1 = atomicAdd(&cur[e4.y & (WSZ - 1)], 1);
            csr_src[q1] = (int)(e4.y >> WB);
            int q2 = atomicAdd(&cur[e4.z & (WSZ - 1)], 1);
            csr_src[q2] = (int)(e4.z >> WB);
            int q3 = atomicAdd(&cur[e4.w & (WSZ - 1)], 1);
            csr_src[q3] = (int)(e4.w >> WB);
        } else {
            for (int j = i; j < s1; ++j) {
                unsigned ep = eb[j];
                int pos = atomicAdd(&cur[ep & (WSZ - 1)], 1);
                csr_src[pos] = (int)(ep >> WB);
            }
        }
    }
}

// ---------------- layer-1 agg: 2 lanes x uint4 per row, 16 edge slots -------
__global__ __launch_bounds__(256) void k_aggx(const unsigned short* __restrict__ xs,
                                              const int* __restrict__ rowptr,
                                              const int* __restrict__ csr_src,
                                              const float* __restrict__ dinv,
                                              unsigned short* __restrict__ xab, int N) {
    int wv = threadIdx.x >> 6;
    int n0 = blockIdx.x * 8 + wv * 2;
    if (n0 >= N) return;
    int lane = threadIdx.x & 63;
    int h = lane >> 5;
    int es = (lane >> 1) & 15;
    int o = lane & 1;
    int n = n0 + h;
    bool valid = (n < N);
    if (!valid) n = n0;
    const uint4* xs4 = (const uint4*)xs;  // row = 2 x uint4 (32 B)
    float a[8] = {0.f, 0.f, 0.f, 0.f, 0.f, 0.f, 0.f, 0.f};
    int s = rowptr[n], e = rowptr[n + 1];
    int i = s;
    while (i + 32 <= e) {
        int idx0 = csr_src[i + es];
        int idx1 = csr_src[i + 16 + es];
        uint4 u0 = xs4[(unsigned)idx0 * 2 + o];
        uint4 u1 = xs4[(unsigned)idx1 * 2 + o];
        addbf8(a, u0);
        addbf8(a, u1);
        i += 32;
    }
    if (i < e) {
        int k0 = i + es, k1 = i + 16 + es;
        float w0 = (k0 < e) ? 1.0f : 0.0f;
        float w1 = (k1 < e) ? 1.0f : 0.0f;
        int i0 = (k0 < e) ? k0 : (e - 1);
        int i1 = (k1 < e) ? k1 : (e - 1);
        int idx0 = csr_src[i0];
        int idx1 = csr_src[i1];
        uint4 u0 = xs4[(unsigned)idx0 * 2 + o];
        uint4 u1 = xs4[(unsigned)idx1 * 2 + o];
        addbf8m(a, u0, w0);
        addbf8m(a, u1, w1);
    }
    #pragma unroll
    for (int j = 0; j < 8; ++j) {
        a[j] += __shfl_xor(a[j], 2);
        a[j] += __shfl_xor(a[j], 4);
        a[j] += __shfl_xor(a[j], 8);
        a[j] += __shfl_xor(a[j], 16);
    }
    if (valid && es == 0) {
        uint4 u = xs4[(unsigned)n * 2 + o];  // self
        addbf8(a, u);
        float dv = dinv[n];
        uint4 st;
        st.x = (unsigned)f2bf(dv * a[0]) | ((unsigned)f2bf(dv * a[1]) << 16);
        st.y = (unsigned)f2bf(dv * a[2]) | ((unsigned)f2bf(dv * a[3]) << 16);
        st.z = (unsigned)f2bf(dv * a[4]) | ((unsigned)f2bf(dv * a[5]) << 16);
        st.w = (unsigned)f2bf(dv * a[6]) | ((unsigned)f2bf(dv * a[7]) << 16);
        *(uint4*)(xab + (size_t)n * 16 + 8 * o) = st;
    }
}

// ---------------- fused layer-1+layer-2 GEMM, W1t LDS-resident --------------
// 128 nodes/block (grid 782), 2 tiles/wave, 3 blocks/CU.
__global__ __launch_bounds__(256, 3) void k_gemm1(const unsigned short* __restrict__ xab,
                                                  const unsigned short* __restrict__ Wint,
                                                  const float* __restrict__ bin,
                                                  const unsigned short* __restrict__ Wt,
                                                  const float* __restrict__ dinv,
                                                  unsigned char* __restrict__ Out, int N) {
    __shared__ unsigned char Wl[32768];      // swizzled W1t
    __shared__ unsigned short H2[4][16 * LDA];
    const int tid = threadIdx.x;
    // cooperative stage: 2048 uint4, xor-swizzled rows (row = byte>>8)
    #pragma unroll
    for (int i2 = 0; i2 < 8; ++i2) {
        int i = tid + i2 * 256;
        uint4 v = ((const uint4*)Wt)[i];
        int b = i * 16;
        *(uint4*)(Wl + (b ^ (((b >> 8) & 7) << 4))) = v;
    }
    const int wave = tid >> 6, lane = tid & 63;
    const int m16 = lane & 15, q = lane >> 4;
    bf16x8 w1r[8];
    #pragma unroll
    for (int t = 0; t < 8; ++t)
        w1r[t] = *(const bf16x8*)(Wint + ((t * 16 + m16) * 32 + q * 8));
    float b1v[8];
    #pragma unroll
    for (int t = 0; t < 8; ++t) b1v[t] = bin[t * 16 + m16];
    __syncthreads();
    unsigned short* h2s = H2[wave];
    const unsigned swz = ((unsigned)(m16 & 7)) << 4;
    #pragma unroll
    for (int tile = 0; tile < 2; ++tile) {
        const int row0 = blockIdx.x * 128 + tile * 64 + wave * 16;
        int arow = row0 + m16;
        if (arow >= N) arow = N - 1;
        bf16x8 a1;
        if (q < 2) a1 = *(const bf16x8*)(xab + (size_t)arow * 16 + q * 8);
        else a1 = (bf16x8){0, 0, 0, 0, 0, 0, 0, 0};
        f32x4 acc1[8];
        #pragma unroll
        for (int t = 0; t < 8; ++t) acc1[t] = (f32x4){0.f, 0.f, 0.f, 0.f};
        #pragma unroll
        for (int t = 0; t < 8; ++t)
            acc1[t] = __builtin_amdgcn_mfma_f32_16x16x32_bf16(a1, w1r[t], acc1[t], 0, 0, 0);
        #pragma unroll
        for (int t = 0; t < 8; ++t) {
            #pragma unroll
            for (int r = 0; r < 4; ++r)
                h2s[(q * 4 + r) * LDA + t * 16 + m16] = f2bf(ftanh(acc1[t][r] + b1v[t]));
        }
        const unsigned short* h2row = h2s + m16 * LDA + q * 8;
        f32x4 acc[8];
        #pragma unroll
        for (int t = 0; t < 8; ++t) acc[t] = (f32x4){0.f, 0.f, 0.f, 0.f};
        #pragma unroll
        for (int kc = 0; kc < 4; ++kc) {
            bf16x8 af = *(const bf16x8*)(h2row + kc * 32);
            #pragma unroll
            for (int t = 0; t < 8; ++t) {
                unsigned wb = (unsigned)((t * 16 + m16) << 8) + (unsigned)(kc * 64 + q * 16);
                bf16x8 wr = *(const bf16x8*)(Wl + (wb ^ swz));
                acc[t] = __builtin_amdgcn_mfma_f32_16x16x32_bf16(af, wr, acc[t], 0, 0, 0);
            }
        }
        float dv[4];
        #pragma unroll
        for (int r = 0; r < 4; ++r) {
            int gr = row0 + q * 4 + r;
            dv[r] = (gr < N) ? dinv[gr] : 0.0f;
        }
        #pragma unroll
        for (int t = 0; t < 8; ++t) {
            #pragma unroll
            for (int r = 0; r < 4; ++r) {
                int gr = row0 + q * 4 + r;
                if (gr < N) Out[(size_t)gr * U + t * 16 + m16] = f2fp8(acc[t][r] * dv[r]);
            }
        }
    }
}

// ---------------- layer-3 GEMM, Wt LDS-resident (128 nodes/blk, 4/CU) -------
__global__ __launch_bounds__(256, 4) void k_gemm2(const unsigned short* __restrict__ A,
                                                  const unsigned short* __restrict__ Wt,
                                                  const float* __restrict__ dinv,
                                                  unsigned char* __restrict__ Out, int N) {
    __shared__ unsigned char Wl[32768];
    const int tid = threadIdx.x;
    #pragma unroll
    for (int i2 = 0; i2 < 8; ++i2) {
        int i = tid + i2 * 256;
        uint4 v = ((const uint4*)Wt)[i];
        int b = i * 16;
        *(uint4*)(Wl + (b ^ (((b >> 8) & 7) << 4))) = v;
    }
    const int wave = tid >> 6, lane = tid & 63;
    const int m16 = lane & 15, q = lane >> 4;
    __syncthreads();
    const unsigned swz = ((unsigned)(m16 & 7)) << 4;
    #pragma unroll
    for (int tile = 0; tile < 2; ++tile) {
        const int row0 = blockIdx.x * 128 + tile * 64 + wave * 16;
        int ar = row0 + m16;
        if (ar >= N) ar = N - 1;
        const bf16x8* arow = (const bf16x8*)(A + (size_t)ar * U + q * 8);
        bf16x8 a[4];
        #pragma unroll
        for (int kc = 0; kc < 4; ++kc) a[kc] = arow[kc * 4];
        f32x4 acc[8];
        #pragma unroll
        for (int t = 0; t < 8; ++t) acc[t] = (f32x4){0.f, 0.f, 0.f, 0.f};
        #pragma unroll
        for (int kc = 0; kc < 4; ++kc) {
            #pragma unroll
            for (int t = 0; t < 8; ++t) {
                unsigned wb = (unsigned)((t * 16 + m16) << 8) + (unsigned)(kc * 64 + q * 16);
                bf16x8 wr = *(const bf16x8*)(Wl + (wb ^ swz));
                acc[t] = __builtin_amdgcn_mfma_f32_16x16x32_bf16(a[kc], wr, acc[t], 0, 0, 0);
            }
        }
        float dv[4];
        #pragma unroll
        for (int r = 0; r < 4; ++r) {
            int gr = row0 + q * 4 + r;
            dv[r] = (gr < N) ? dinv[gr] : 0.0f;
        }
        #pragma unroll
        for (int t = 0; t < 8; ++t) {
            #pragma unroll
            for (int r = 0; r < 4; ++r) {
                int gr = row0 + q * 4 + r;
                if (gr < N) Out[(size_t)gr * U + t * 16 + m16] = f2fp8(acc[t][r] * dv[r]);
            }
        }
    }
}

// ---------------- aggregation (fp8 table): uint4 rows, half-wave per node ---
__global__ __launch_bounds__(256) void k_aggb(const unsigned char* __restrict__ Tb,
                                              const int* __restrict__ rowptr,
                                              const int* __restrict__ csr_src,
                                              const float* __restrict__ dinv,
                                              const float* __restrict__ bias,
                                              unsigned short* __restrict__ Out, int N) {
    int wv = threadIdx.x >> 6;
    int n0 = blockIdx.x * 8 + wv * 2;
    if (n0 >= N) return;
    int lane = threadIdx.x & 63;
    int h = lane >> 5;
    int q = (lane >> 3) & 3;
    int o = lane & 7;
    int n = n0 + h;
    bool valid = (n < N);
    if (!valid) n = n0;
    const char* Tc = (const char*)Tb;
    const unsigned loff = (unsigned)o << 4;  // byte offset of my uint4 in row
    f32x2 acc[8];
    #pragma unroll
    for (int j = 0; j < 8; ++j) acc[j] = (f32x2){0.f, 0.f};
    int s = rowptr[n], e = rowptr[n + 1];
    int i = s;
    while (i + 16 <= e) {
        int idx[4];
        #pragma unroll
        for (int g2 = 0; g2 < 4; ++g2) idx[g2] = csr_src[i + g2 * 4 + q];
        uint4 u[4];
        #pragma unroll
        for (int g2 = 0; g2 < 4; ++g2)
            u[g2] = *(const uint4*)(Tc + (((unsigned)idx[g2] << 7) + loff));
        #pragma unroll
        for (int g2 = 0; g2 < 4; ++g2) acc16(acc, u[g2]);
        i += 16;
    }
    if (i < e) {
        int ii[4];
        float w[4];
        #pragma unroll
        for (int g2 = 0; g2 < 4; ++g2) {
            int k = i + g2 * 4 + q;
            w[g2] = (k < e) ? 1.0f : 0.0f;
            ii[g2] = (k < e) ? k : (e - 1);
        }
        int idx[4];
        #pragma unroll
        for (int g2 = 0; g2 < 4; ++g2) idx[g2] = csr_src[ii[g2]];
        uint4 u[4];
        #pragma unroll
        for (int g2 = 0; g2 < 4; ++g2)
            u[g2] = *(const uint4*)(Tc + (((unsigned)idx[g2] << 7) + loff));
        #pragma unroll
        for (int g2 = 0; g2 < 4; ++g2) acc16m(acc, u[g2], w[g2]);
    }
    float* af = (float*)acc;
    #pragma unroll
    for (int j = 0; j < 16; ++j) {
        af[j] += __shfl_xor(af[j], 8);
        af[j] += __shfl_xor(af[j], 16);
    }
    f32x2 vA = (q < 2) ? ((q == 0) ? acc[0] : acc[2]) : ((q == 2) ? acc[4] : acc[6]);
    f32x2 vB = (q < 2) ? ((q == 0) ? acc[1] : acc[3]) : ((q == 2) ? acc[5] : acc[7]);
    int f = 16 * o + 4 * q;
    float4 bb = *(const float4*)&bias[f];
    float dv = dinv[n];
    unsigned selfu = *(const unsigned*)(Tc + ((unsigned)n << 7) + f);
    f32x2 s01 = __builtin_amdgcn_cvt_pk_f32_fp8(selfu, false);
    f32x2 s23 = __builtin_amdgcn_cvt_pk_f32_fp8(selfu, true);
    float o0 = ftanh(dv * (vA[0] + s01[0]) + bb.x);
    float o1 = ftanh(dv * (vA[1] + s01[1]) + bb.y);
    float o2 = ftanh(dv * (vB[0] + s23[0]) + bb.z);
    float o3 = ftanh(dv * (vB[1] + s23[1]) + bb.w);
    if (valid) {
        uint2 st;
        st.x = (unsigned)f2bf(o0) | ((unsigned)f2bf(o1) << 16);
        st.y = (unsigned)f2bf(o2) | ((unsigned)f2bf(o3) << 16);
        *(uint2*)((char*)Out + ((size_t)n << 8) + ((unsigned)f << 1)) = st;
    }
}

// ---------------- fused MFMA MLP head v2 (as R9) ----------------
__global__ __launch_bounds__(256, 2) void k_mlp(const unsigned short* __restrict__ H,
                                                const unsigned short* __restrict__ Wf1t,
                                                const float* __restrict__ bf1,
                                                const unsigned short* __restrict__ Wf2t,
                                                const float* __restrict__ bf2,
                                                const float* __restrict__ Wf3,
                                                const float* __restrict__ bf3,
                                                const int* __restrict__ batch,
                                                float* __restrict__ util_sum,
                                                int N, int G) {
    __shared__ unsigned short H2[4][16 * LDA];  // per-wave transpose slice
    __shared__ float gsum[8];
    const int tid = threadIdx.x;
    if (tid < 8) gsum[tid] = 0.0f;
    const int wave = tid >> 6, lane = tid & 63;
    const int m16 = lane & 15, q = lane >> 4;
    const int blk0 = blockIdx.x * 256;
    const int g0 = batch[min(blk0, N - 1)];
    bf16x8 w1[4][8], w2[4][2];
    #pragma unroll
    for (int kc = 0; kc < 4; ++kc) {
        #pragma unroll
        for (int t = 0; t < 8; ++t)
            w1[kc][t] = *(const bf16x8*)(Wf1t + ((t * 16 + m16) * 128 + kc * 32 + q * 8));
        #pragma unroll
        for (int t = 0; t < 2; ++t)
            w2[kc][t] = *(const bf16x8*)(Wf2t + ((t * 16 + m16) * 128 + kc * 32 + q * 8));
    }
    float b1v[8];
    #pragma unroll
    for (int t = 0; t < 8; ++t) b1v[t] = bf1[t * 16 + m16];
    const float b2lo = bf2[m16], b2hi = bf2[m16 + 16];
    const float w3lo = Wf3[m16], w3hi = Wf3[m16 + 16];
    const float bf3v = bf3[0];
    __syncthreads();  // gsum init visible before tile atomics
    unsigned short* h2s = H2[wave];
    const int wbase = blk0 + wave * 64;
    bf16x8 a[4];
    {
        int ar = wbase + m16;
        if (ar >= N) ar = N - 1;
        const bf16x8* arow = (const bf16x8*)(H + (size_t)ar * U + q * 8);
        #pragma unroll
        for (int kc = 0; kc < 4; ++kc) a[kc] = arow[kc * 4];
    }
    for (int tile = 0; tile < 4; ++tile) {
        const int row0 = wbase + tile * 16;
        bf16x8 an[4];
        if (tile < 3) {
            int ar = row0 + 16 + m16;
            if (ar >= N) ar = N - 1;
            const bf16x8* arow = (const bf16x8*)(H + (size_t)ar * U + q * 8);
            #pragma unroll
            for (int kc = 0; kc < 4; ++kc) an[kc] = arow[kc * 4];
        }
        f32x4 acc[8];
        #pragma unroll
        for (int t = 0; t < 8; ++t) acc[t] = (f32x4){0.f, 0.f, 0.f, 0.f};
        #pragma unroll
        for (int kc = 0; kc < 4; ++kc) {
            #pragma unroll
            for (int t = 0; t < 8; ++t)
                acc[t] = __builtin_amdgcn_mfma_f32_16x16x32_bf16(a[kc], w1[kc][t], acc[t], 0, 0, 0);
        }
        #pragma unroll
        for (int t = 0; t < 8; ++t) {
            #pragma unroll
            for (int r = 0; r < 4; ++r) {
                int lr = q * 4 + r;
                h2s[lr * LDA + t * 16 + m16] = f2bf(ftanh(acc[t][r] + b1v[t]));
            }
        }
        f32x4 acc2[2];
        acc2[0] = (f32x4){0.f, 0.f, 0.f, 0.f};
        acc2[1] = (f32x4){0.f, 0.f, 0.f, 0.f};
        const unsigned short* h2row = h2s + m16 * LDA + q * 8;
        #pragma unroll
        for (int kc = 0; kc < 4; ++kc) {
            bf16x8 af = *(const bf16x8*)(h2row + kc * 32);
            #pragma unroll
            for (int t = 0; t < 2; ++t)
                acc2[t] = __builtin_amdgcn_mfma_f32_16x16x32_bf16(af, w2[kc][t], acc2[t], 0, 0, 0);
        }
        #pragma unroll
        for (int r = 0; r < 4; ++r) {
            float t0 = ftanh(acc2[0][r] + b2lo);
            float t1 = ftanh(acc2[1][r] + b2hi);
            float v = t0 * w3lo + t1 * w3hi;
            v += __shfl_xor(v, 1);
            v += __shfl_xor(v, 2);
            v += __shfl_xor(v, 4);
            v += __shfl_xor(v, 8);
            if (m16 == 0) {
                int n = row0 + q * 4 + r;
                if (n < N) atomicAdd(&gsum[batch[n] - g0], v + bf3v);
            }
        }
        #pragma unroll
        for (int kc = 0; kc < 4; ++kc) a[kc] = an[kc];
    }
    __syncthreads();
    if (tid < 8) {
        int g = g0 + tid;
        if (g < G) {
            float s = gsum[tid];
            if (s != 0.0f) atomicAdd(&util_sum[g], s);
        }
    }
}

// ---------------- fused output: util + pair sigmoid ----------------
__global__ void k_out(const float* __restrict__ us, const int* __restrict__ cnt,
                      const int* __restrict__ ia, const int* __restrict__ ib,
                      float* __restrict__ out, int P, int G) {
    int t = blockIdx.x * 256 + threadIdx.x;
    if (t < G) out[P + t] = us[t] / fmaxf((float)cnt[t], 1.0f);
    if (t < P) {
        int a = ia[t], b = ib[t];
        float ua = us[a] / fmaxf((float)cnt[a], 1.0f);
        float ub = us[b] / fmaxf((float)cnt[b], 1.0f);
        out[t] = 1.0f / (1.0f + expf(-(ub - ua)));
    }
}

extern "C" void kernel_launch(void* const* d_in, const int* in_sizes, int n_in,
                              void* d_out, int out_size, void* d_ws, size_t ws_size,
                              hipStream_t stream) {
    const float* x     = (const float*)d_in[0];
    const int*   eidx  = (const int*)d_in[1];
    const int*   batch = (const int*)d_in[2];
    const int*   idx_a = (const int*)d_in[3];
    const int*   idx_b = (const int*)d_in[4];
    const float* W_in  = (const float*)d_in[5];
    const float* b_in  = (const float*)d_in[6];
    const float* W1    = (const float*)d_in[7];
    const float* b1    = (const float*)d_in[8];
    const float* W2    = (const float*)d_in[9];
    const float* b2    = (const float*)d_in[10];
    const float* Wf1   = (const float*)d_in[11];
    const float* bf1   = (const float*)d_in[12];
    const float* Wf2   = (const float*)d_in[13];
    const float* bf2   = (const float*)d_in[14];
    const float* Wf3   = (const float*)d_in[15];
    const float* bf3   = (const float*)d_in[16];
    float* out = (float*)d_out;

    const int N = in_sizes[0] / 9;
    const int E = in_sizes[1] / 2;
    const int P = in_sizes[3];
    const int G = out_size - P;

    const int* src = eidx;
    const int* dst = eidx + E;

    const int nw = (N + WSZ - 1) >> WB;  // level-2 windows (196 for N=100k)
    const int nh = nw * NJ1;             // hist_g size
    const int nbh = (nh + 1023) / 1024;  // scan blocks for hist_g

    // ---- workspace carve-out ----
    char* ws = (char*)d_ws;
    size_t off = 0;
    auto take = [&](size_t bytes) -> void* {
        void* p = ws + off;
        off = (off + bytes + 255) & ~(size_t)255;
        return p;
    };
    float* dinv     = (float*)take((size_t)N * 4);
    int*   rowptr   = (int*)  take((size_t)(N + 1) * 4);
    int*   bsum2    = (int*)  take(256 * 4);
    int*   hist_g   = (int*)  take((size_t)nh * 4);
    unsigned* eb    = (unsigned*)take((size_t)E * 4);   // packed (src<<9)|dloc
    int*   csr_src  = (int*)  take((size_t)E * 4);
    unsigned short* xs  = (unsigned short*)take((size_t)N * 16 * 2);  // bf16 32B rows
    unsigned short* xab = (unsigned short*)take((size_t)N * 16 * 2);  // bf16 A-frag rows
    unsigned short* bufA = (unsigned short*)take((size_t)N * U * 2);  // bf16 acts
    unsigned char*  Tb   = (unsigned char*) take((size_t)N * U);      // fp8 table
    unsigned short* Wint = (unsigned short*)take(128 * 32 * 2);       // W_in^T pad K=32
    unsigned short* W1t  = (unsigned short*)take(128 * 128 * 2);
    unsigned short* W2t  = (unsigned short*)take(128 * 128 * 2);
    unsigned short* Wf1t = (unsigned short*)take(128 * 128 * 2);
    unsigned short* Wf2t = (unsigned short*)take(32 * 128 * 2);
    // zero-region: util_sum + cnt contiguous, single memset
    float* util_sum = (float*)take((size_t)G * 8);
    int*   cnt      = (int*)(util_sum + G);
    (void)ws_size;

    hipMemsetAsync(util_sum, 0, (size_t)G * 8, stream);

    // ---- CSR build: two-level counting sort, fused window CSR ----
    k_hist1<<<NJ1, 256, 0, stream>>>(dst, hist_g, W_in, W1, W2, Wf1, Wf2,
                                     Wint, W1t, W2t, Wf1t, Wf2t, E, nw);
    k_escan1<<<nbh, 256, 0, stream>>>(hist_g, bsum2, nh);
    k_scanb<<<1, 256, 0, stream>>>(bsum2, nbh);
    k_bucket<<<NJ1, 256, 0, stream>>>(src, dst, hist_g, bsum2, eb, E, nw);
    k_csr<<<nw, 256, 0, stream>>>(eb, hist_g, bsum2, x, batch, rowptr, csr_src,
                                  dinv, xs, cnt, E, nw, N, G);

    const int gemmGrid = (N + 127) / 128;  // 128 nodes/block (grid 782)
    const int aggGrid = (N + 7) / 8;       // 2 nodes/wave, 8 nodes/block

    // ---- GCN layer 1 agg + fused layer-1/layer-2 GEMM -> fp8 ----
    k_aggx<<<aggGrid, 256, 0, stream>>>(xs, rowptr, csr_src, dinv, xab, N);
    k_gemm1<<<gemmGrid, 256, 0, stream>>>(xab, Wint, b_in, W1t, dinv, Tb, N);
    k_aggb<<<aggGrid, 256, 0, stream>>>(Tb, rowptr, csr_src, dinv, b1, bufA, N);
    // ---- GCN layer 3 ----
    k_gemm2<<<gemmGrid, 256, 0, stream>>>(bufA, W2t, dinv, Tb, N);
    k_aggb<<<aggGrid, 256, 0, stream>>>(Tb, rowptr, csr_src, dinv, b2, bufA, N);

    // ---- MLP head + pooled sums (256 nodes/block) ----
    k_mlp<<<(N + 255) / 256, 256, 0, stream>>>(bufA, Wf1t, bf1, Wf2t, bf2, Wf3, bf3,
                                               batch, util_sum, N, G);

    // ---- fused util + pairs ----
    int mx = (P > G ? P : G);
    k_out<<<(mx + 255) / 256, 256, 0, stream>>>(util_sum, cnt, idx_a, idx_b, out, P, G);
}